// Round 11
// baseline (586.016 us; speedup 1.0000x reference)
//
#include <hip/hip_runtime.h>

typedef unsigned short u16;
typedef __attribute__((ext_vector_type(8))) short bf16x8;
typedef __attribute__((ext_vector_type(8))) unsigned short u16x8;
typedef __attribute__((ext_vector_type(4))) unsigned short u16x4;
typedef __attribute__((ext_vector_type(4))) float f32x4;

#define NB 4
#define NH 12
#define NSEQ 4096
#define NC 768
#define ND 64
#define NM 64
#define NBH 48

__device__ __forceinline__ float b2f(u16 u){ unsigned v = ((unsigned)u)<<16; return __builtin_bit_cast(float, v); }
__device__ __forceinline__ u16 f2b(float f){ unsigned u = __builtin_bit_cast(unsigned, f); u = u + 0x7FFFu + ((u>>16)&1u); return (u16)(u>>16); }
__device__ __forceinline__ void split2(float f, u16& h, u16& l){
  h = f2b(f);
  l = f2b(f - b2f(h));
}

typedef const __attribute__((address_space(1))) unsigned int guint;
typedef __attribute__((address_space(3))) unsigned int luint;
__device__ __forceinline__ void gload16(const void* g, void* l){
  __builtin_amdgcn_global_load_lds((guint*)g, (luint*)l, 16, 0, 0);
}

__device__ __forceinline__ f32x4 mfma16x16(bf16x8 a, bf16x8 b, f32x4 c){
  return __builtin_amdgcn_mfma_f32_16x16x32_bf16(a, b, c, 0, 0, 0);
}

// ---------------- merged split: f32 -> (hi,lo) bf16 pairs for x, wqkv, wproj ----------------
#define NX4 3145728
#define NWQ4 442368
#define NWP4 147456
__global__ __launch_bounds__(256) void k_split3(const float* __restrict__ x, const float* __restrict__ wq,
                                                const float* __restrict__ wp,
                                                u16* __restrict__ xh, u16* __restrict__ xl,
                                                u16* __restrict__ wqh, u16* __restrict__ wql,
                                                u16* __restrict__ wph, u16* __restrict__ wpl){
  int i = blockIdx.x*256 + threadIdx.x;
  const float* src; u16 *dh, *dl; int j;
  if (i < NX4){ src = x; dh = xh; dl = xl; j = i; }
  else if (i < NX4+NWQ4){ src = wq; dh = wqh; dl = wql; j = i - NX4; }
  else if (i < NX4+NWQ4+NWP4){ src = wp; dh = wph; dl = wpl; j = i - NX4 - NWQ4; }
  else return;
  f32x4 v = ((const f32x4*)src)[j];
  u16x4 hh, ll;
  #pragma unroll
  for (int e=0;e<4;++e){ u16 hb, lb; split2(v[e], hb, lb); hh[e]=hb; ll[e]=lb; }
  ((u16x4*)dh)[j] = hh; ((u16x4*)dl)[j] = ll;
}

// ============ k_qkv8: 256x256 tile, BK=32, ring-4 LDS dbuf, counted vmcnt(8) ============
// qkv = Xh@Wh^T + Xh@Wl^T + Xl@Wh^T  as one K=2304 GEMM (3 ranges of 768).
// 72 K-tiles of 32; tile t in buf[t&3]; stage tile t+3 during t (A-pair phase0, B-pair phase1);
// entry wait vmcnt(8) (=loads of t+1,t+2 outstanding), tail 4/0. LDS swizzle slot^((row>>1)&3).
__global__ __launch_bounds__(512,2) void k_qkv8(const u16* __restrict__ xh, const u16* __restrict__ xl,
                                                const u16* __restrict__ wh, const u16* __restrict__ wl,
                                                u16* __restrict__ qh, u16* __restrict__ ql,
                                                u16* __restrict__ kh, u16* __restrict__ kl,
                                                u16* __restrict__ vTh, u16* __restrict__ vTl,
                                                float* __restrict__ qlmf, float* __restrict__ klmf,
                                                u16* __restrict__ qlmh, u16* __restrict__ qlml,
                                                u16* __restrict__ klmh, u16* __restrict__ klml){
  __shared__ u16 lds[65536];            // 128 KB: 4 bufs x (A 8192 | B 8192) u16
  int tid = threadIdx.x, wave = tid>>6, lane = tid&63;
  int wm = wave>>2, wn = wave&3;        // 2M x 4N waves; wave tile 128x64
  int bid = blockIdx.x;                 // 576 blocks (64 by x 9 bx), %8==0
  int swz = (bid&7)*72 + (bid>>3);      // bijective XCD swizzle
  int bx = swz % 9, by = swz / 9;       // n-fastest within XCD chunk
  int m0 = by*256, n0 = bx*256;
  // ---- staging pointers (per thread): row=pass*128+(tid>>2), slot=tid&3, pre-swizzled col ----
  int trow = tid>>2, tslot = tid&3;
  int gs = (tslot ^ ((trow>>1)&3))*8;
  const u16* aXh0 = xh + (size_t)(m0+trow)*NC + gs;
  const u16* aXh1 = xh + (size_t)(m0+128+trow)*NC + gs;
  const u16* aXl0 = xl + (size_t)(m0+trow)*NC + gs;
  const u16* aXl1 = xl + (size_t)(m0+128+trow)*NC + gs;
  const u16* bWh0 = wh + (size_t)(n0+trow)*NC + gs;
  const u16* bWh1 = wh + (size_t)(n0+128+trow)*NC + gs;
  const u16* bWl0 = wl + (size_t)(n0+trow)*NC + gs;
  const u16* bWl1 = wl + (size_t)(n0+128+trow)*NC + gs;
  auto stageA = [&](int tt){
    int seg = tt/24, kc = (tt%24)*32, bo = (tt&3)*16384;
    const u16* p0 = (seg==2)? aXl0 : aXh0;
    const u16* p1 = (seg==2)? aXl1 : aXh1;
    gload16(p0+kc, &lds[bo + wave*512]);
    gload16(p1+kc, &lds[bo + 4096 + wave*512]);
  };
  auto stageB = [&](int tt){
    int seg = tt/24, kc = (tt%24)*32, bo = (tt&3)*16384;
    const u16* p0 = (seg==1)? bWl0 : bWh0;
    const u16* p1 = (seg==1)? bWl1 : bWh1;
    gload16(p0+kc, &lds[bo + 8192 + wave*512]);
    gload16(p1+kc, &lds[bo + 8192 + 4096 + wave*512]);
  };
  // ---- fragment read constants ----
  int la = lane&15;
  int sl = ((lane>>4) ^ ((la>>1)&3))*8;   // swizzled K-slot (same for all fragment rows)
  f32x4 acc[8][4] = {};
  // ---- prologue: stage tiles 0,1,2 ----
  stageA(0); stageB(0); stageA(1); stageB(1); stageA(2); stageB(2);
  // ---- main loop: 72 tiles x 2 phases ----
  for (int t=0; t<72; ++t){
    if (t < 70)      asm volatile("s_waitcnt vmcnt(8)" ::: "memory");
    else if (t==70)  asm volatile("s_waitcnt vmcnt(4)" ::: "memory");
    else             asm volatile("s_waitcnt vmcnt(0)" ::: "memory");
    __builtin_amdgcn_s_barrier();
    __builtin_amdgcn_sched_barrier(0);
    int bo = (t&3)*16384;
    bool st = (t <= 68);
    bf16x8 av[4], bv[4];
    #pragma unroll
    for (int j=0;j<4;++j) bv[j] = *(const bf16x8*)&lds[bo + 8192 + (wn*64 + j*16 + la)*32 + sl];
    #pragma unroll
    for (int i=0;i<4;++i) av[i] = *(const bf16x8*)&lds[bo + (wm*128 + i*16 + la)*32 + sl];
    if (st) stageA(t+3);
    __builtin_amdgcn_s_setprio(1);
    #pragma unroll
    for (int i=0;i<4;++i)
      #pragma unroll
      for (int j=0;j<4;++j) acc[i][j] = mfma16x16(av[i], bv[j], acc[i][j]);
    __builtin_amdgcn_s_setprio(0);
    __builtin_amdgcn_s_barrier();
    #pragma unroll
    for (int i=0;i<4;++i) av[i] = *(const bf16x8*)&lds[bo + (wm*128 + 64 + i*16 + la)*32 + sl];
    if (st) stageB(t+3);
    __builtin_amdgcn_s_setprio(1);
    #pragma unroll
    for (int i=0;i<4;++i)
      #pragma unroll
      for (int j=0;j<4;++j) acc[4+i][j] = mfma16x16(av[i], bv[j], acc[4+i][j]);
    __builtin_amdgcn_s_setprio(0);
  }
  // ---- epilogue ----
  int rb = (lane>>4)*4, cb = lane&15;
  int b_ = m0>>12, nlo = m0&4095;
  if (n0 < 1536){
    // q or k block (bx 0-2 -> q, 3-5 -> k): row-major stores + fused segment pooling
    int s = n0/768;
    u16* dh = s ? kh : qh;
    u16* dl = s ? kl : ql;
    float* lmf = s ? klmf : qlmf;
    u16* lmh = s ? klmh : qlmh;
    u16* lml = s ? klml : qlml;
    #pragma unroll
    for (int j=0;j<4;++j){
      int gn = n0 + wn*64 + j*16 + cb;
      int rem = gn - s*768; int hd = rem>>6, d = rem&63;
      #pragma unroll
      for (int qi=0; qi<2; ++qi){
        float tot = 0.f;
        #pragma unroll
        for (int i=0;i<4;++i)
          #pragma unroll
          for (int r=0;r<4;++r){
            float v = acc[qi*4+i][j][r];
            int n = nlo + wm*128 + qi*64 + i*16 + rb + r;
            size_t idx = (((size_t)(b_*NH + hd))*NSEQ + n)*ND + d;
            u16 hb, lb; split2(v, hb, lb);
            dh[idx] = hb; dl[idx] = lb;
            tot += v;
          }
        tot += __shfl_xor(tot, 16);
        tot += __shfl_xor(tot, 32);
        if (lane < 16){
          int lseg = (nlo>>6) + wm*2 + qi;
          float mean = tot * (1.f/64.f);
          size_t o = (((size_t)(b_*NH + hd))*NM + lseg)*ND + d;
          lmf[o] = mean;
          u16 hb, lb; split2(mean, hb, lb);
          lmh[o] = hb; lml[o] = lb;
        }
      }
    }
  } else {
    // v block (bx 6-8): transpose 256x256 tile via LDS in 4 guarded passes
    #pragma unroll
    for (int part=0; part<2; ++part){
      #pragma unroll
      for (int p=0; p<2; ++p){
        __syncthreads();
        if ((wn>>1) == p){
          int dbase = (wn&1)*64;
          #pragma unroll
          for (int j=0;j<4;++j){
            int dcol = dbase + j*16 + cb;
            #pragma unroll
            for (int qi=0;qi<2;++qi)
              #pragma unroll
              for (int i=0;i<4;++i)
                #pragma unroll
                for (int r=0;r<4;++r){
                  int row = wm*128 + qi*64 + i*16 + rb + r;
                  u16 hb, lb; split2(acc[qi*4+i][j][r], hb, lb);
                  lds[dcol*264 + row] = part ? lb : hb;
                }
          }
        }
        __syncthreads();
        int dloc = tid>>2, seg = tid&3;
        int vcol = (n0 - 1536) + p*128 + dloc;
        int hd = vcol>>6, dd = vcol&63;
        u16* dst = (part ? vTl : vTh) + (((size_t)(b_*NH + hd))*ND + dd)*NSEQ + nlo + seg*64;
        const u16* srcl = &lds[dloc*264 + seg*64];
        #pragma unroll
        for (int e=0;e<8;++e)
          *(u16x8*)(dst + e*8) = *(const u16x8*)(srcl + e*8);
      }
    }
  }
}

// ---------------- big GEMM 2: out = H @ Wproj^T + bias (f32 out) ----------------
__global__ __launch_bounds__(256) void k_proj(const u16* __restrict__ Hh, const u16* __restrict__ Hl,
                                              const u16* __restrict__ wh, const u16* __restrict__ wl,
                                              const float* __restrict__ bias, float* __restrict__ out){
  __shared__ u16 lds[32768];
  const int K = NC;
  int tid = threadIdx.x, wave = tid>>6, lane = tid&63;
  int wm = wave>>1, wn = wave&1;
  int bid = blockIdx.x;                    // 768 blocks, %8==0
  int swz = (bid&7)*96 + (bid>>3);
  int bx = swz % 6, by = swz / 6;
  int m0 = by*128, n0 = bx*128;
  int srow = lane>>3;
  int scol = ((lane&7) ^ srow)*8;
  const u16* src0; u16* dst0;
  if (wave==0){ src0 = Hh + (size_t)m0*K; dst0 = lds; }
  else if (wave==1){ src0 = Hl + (size_t)m0*K; dst0 = lds+8192; }
  else if (wave==2){ src0 = wh + (size_t)n0*K; dst0 = lds+16384; }
  else            { src0 = wl + (size_t)n0*K; dst0 = lds+24576; }
  f32x4 acc[4][4] = {};
  for (int k0=0; k0<K; k0+=64){
    #pragma unroll
    for (int it=0; it<16; ++it){
      int r = it*8;
      gload16(&src0[(size_t)(r+srow)*K + k0 + scol], &dst0[r*64]);
    }
    __syncthreads();
    #pragma unroll
    for (int kk=0; kk<2; ++kk){
      int sl = ((kk*4 + (lane>>4)) ^ (lane&7))*8;
      bf16x8 a_h[4], a_l[4], b_h[4], b_l[4];
      #pragma unroll
      for (int i=0;i<4;++i){
        int ro = (wm*64+i*16+(lane&15))*64 + sl;
        a_h[i] = *(const bf16x8*)&lds[ro]; a_l[i] = *(const bf16x8*)&lds[8192+ro];
      }
      #pragma unroll
      for (int j=0;j<4;++j){
        int ro = (wn*64+j*16+(lane&15))*64 + sl;
        b_h[j] = *(const bf16x8*)&lds[16384+ro]; b_l[j] = *(const bf16x8*)&lds[24576+ro];
      }
      #pragma unroll
      for (int i=0;i<4;++i)
        #pragma unroll
        for (int j=0;j<4;++j){
          acc[i][j] = mfma16x16(a_h[i], b_h[j], acc[i][j]);
          acc[i][j] = mfma16x16(a_h[i], b_l[j], acc[i][j]);
          acc[i][j] = mfma16x16(a_l[i], b_h[j], acc[i][j]);
        }
    }
    __syncthreads();
  }
  int rb = (lane>>4)*4, cb = lane&15;
  #pragma unroll
  for (int j=0;j<4;++j){
    int gn = n0 + wn*64 + j*16 + cb;
    float bb = bias[gn];
    #pragma unroll
    for (int i=0;i<4;++i){
      #pragma unroll
      for (int r=0;r<4;++r){
        int gm = m0 + wm*64 + i*16 + rb + r;
        out[(size_t)gm*NC + gn] = acc[i][j][r] + bb;
      }
    }
  }
}

// ---------------- s2 = q_lm @ k^T * scale -> f32 [BH][64][4096], + per-block softmax partials ----------------
__global__ __launch_bounds__(256) void k_s2(const u16* __restrict__ qlmh, const u16* __restrict__ qlml,
                                            const u16* __restrict__ kh, const u16* __restrict__ kl,
                                            float* __restrict__ s2f, float* __restrict__ stats){
  int chunk = blockIdx.x, bh = blockIdx.y;
  int tid = threadIdx.x, wave = tid>>6, lane = tid&63;
  const u16* Ahp = qlmh + (size_t)bh*NM*ND;
  const u16* Alp = qlml + (size_t)bh*NM*ND;
  const u16* Bhp = kh + (size_t)bh*NSEQ*ND;
  const u16* Blp = kl + (size_t)bh*NSEQ*ND;
  int nbase = chunk*256 + wave*64;
  f32x4 acc[4][4] = {};
  #pragma unroll
  for (int kk=0; kk<2; ++kk){
    int koff = kk*32 + (lane>>4)*8;
    bf16x8 a_h[4], a_l[4], b_h[4], b_l[4];
    #pragma unroll
    for (int i=0;i<4;++i){
      size_t ro = (size_t)(i*16+(lane&15))*ND + koff;
      a_h[i] = *(const bf16x8*)&Ahp[ro]; a_l[i] = *(const bf16x8*)&Alp[ro];
    }
    #pragma unroll
    for (int j=0;j<4;++j){
      size_t ro = (size_t)(nbase + j*16 + (lane&15))*ND + koff;
      b_h[j] = *(const bf16x8*)&Bhp[ro]; b_l[j] = *(const bf16x8*)&Blp[ro];
    }
    #pragma unroll
    for (int i=0;i<4;++i)
      #pragma unroll
      for (int j=0;j<4;++j){
        acc[i][j] = mfma16x16(a_h[i], b_h[j], acc[i][j]);
        acc[i][j] = mfma16x16(a_h[i], b_l[j], acc[i][j]);
        acc[i][j] = mfma16x16(a_l[i], b_h[j], acc[i][j]);
      }
  }
  int rb = (lane>>4)*4, cb = lane&15;
  #pragma unroll
  for (int i=0;i<4;++i)
    #pragma unroll
    for (int j=0;j<4;++j)
      #pragma unroll
      for (int r=0;r<4;++r){
        int l = i*16 + rb + r; int n = nbase + j*16 + cb;
        s2f[((size_t)bh*NM + l)*NSEQ + n] = acc[i][j][r]*0.125f;
      }
  #pragma unroll
  for (int i=0;i<4;++i)
    #pragma unroll
    for (int r=0;r<4;++r){
      float v0 = acc[i][0][r]*0.125f, v1 = acc[i][1][r]*0.125f;
      float v2 = acc[i][2][r]*0.125f, v3 = acc[i][3][r]*0.125f;
      float mx = fmaxf(fmaxf(v0,v1), fmaxf(v2,v3));
      #pragma unroll
      for (int off=1; off<16; off<<=1) mx = fmaxf(mx, __shfl_xor(mx, off));
      float se = __expf(v0-mx)+__expf(v1-mx)+__expf(v2-mx)+__expf(v3-mx);
      #pragma unroll
      for (int off=1; off<16; off<<=1) se += __shfl_xor(se, off);
      if (cb == 0){
        int row = i*16 + rb + r;
        size_t o = ((((size_t)chunk*NBH + bh)*4 + wave)*64 + row)*2;
        stats[o] = mx; stats[o+1] = se;
      }
    }
}

// ---------------- t1 partials with inline softmax ----------------
__global__ __launch_bounds__(256) void k_t1(const float* __restrict__ s2f, const float* __restrict__ stats,
                                            const u16* __restrict__ vTh, const u16* __restrict__ vTl,
                                            float* __restrict__ t1p){
  int kb = blockIdx.x, bh = blockIdx.y;
  int tid = threadIdx.x, wave = tid>>6, lane = tid&63;
  int arow = wave*16 + (lane&15);
  float MX = -1e30f;
  for (int c=0;c<16;++c)
    #pragma unroll
    for (int w=0;w<4;++w)
      MX = fmaxf(MX, stats[((((size_t)c*NBH + bh)*4 + w)*64 + arow)*2]);
  float SE = 0.f;
  for (int c=0;c<16;++c)
    #pragma unroll
    for (int w=0;w<4;++w){
      size_t o = ((((size_t)c*NBH + bh)*4 + w)*64 + arow)*2;
      SE += stats[o+1]*__expf(stats[o]-MX);
    }
  float INV = 1.f/SE;
  const float* srow = s2f + ((size_t)bh*NM + arow)*NSEQ;
  const u16* Bh = vTh + (size_t)bh*ND*NSEQ;
  const u16* Bl = vTl + (size_t)bh*ND*NSEQ;
  f32x4 acc[4] = {};
  for (int ks=0; ks<16; ++ks){
    int koff = kb*512 + ks*32 + (lane>>4)*8;
    f32x4 sv0 = *(const f32x4*)&srow[koff];
    f32x4 sv1 = *(const f32x4*)&srow[koff+4];
    bf16x8 a_h, a_l;
    #pragma unroll
    for (int e=0;e<4;++e){
      u16 hb, lb;
      split2(__expf(sv0[e]-MX)*INV, hb, lb); a_h[e]   = (short)hb; a_l[e]   = (short)lb;
      split2(__expf(sv1[e]-MX)*INV, hb, lb); a_h[4+e] = (short)hb; a_l[4+e] = (short)lb;
    }
    #pragma unroll
    for (int j=0;j<4;++j){
      size_t ro = (size_t)(j*16+(lane&15))*NSEQ + koff;
      bf16x8 b_h = *(const bf16x8*)&Bh[ro];
      bf16x8 b_l = *(const bf16x8*)&Bl[ro];
      acc[j] = mfma16x16(a_h, b_h, acc[j]);
      acc[j] = mfma16x16(a_h, b_l, acc[j]);
      acc[j] = mfma16x16(a_l, b_h, acc[j]);
    }
  }
  int rb = (lane>>4)*4, cb = lane&15;
  #pragma unroll
  for (int j=0;j<4;++j)
    #pragma unroll
    for (int r=0;r<4;++r){
      int l = wave*16 + rb + r; int d = j*16 + cb;
      t1p[((size_t)(kb*NBH + bh)*NM + l)*ND + d] = acc[j][r];
    }
}

// ---------------- mid (4-wave): Gram+softmax -> M; T = sum t1p; GJ solve [M|T] -> X; write X^T pair
__global__ __launch_bounds__(256) void k_mid(const float* __restrict__ qlmf, const float* __restrict__ klmf,
                                            const float* __restrict__ t1p,
                                            u16* __restrict__ w2th, u16* __restrict__ w2tl){
  __shared__ float M[64*68];
  __shared__ float T[64*68];
  __shared__ int piv_s;
  int bh = blockIdx.x, tid = threadIdx.x;
  int r = tid>>2, qd = tid&3;           // row, 16-col quad
  const float* qrow  = qlmf + (size_t)bh*NM*ND + r*64;
  const float* kbase = klmf + (size_t)bh*NM*ND;
  float qv[64];
  #pragma unroll
  for (int e=0;e<16;++e){
    f32x4 t4 = ((const f32x4*)qrow)[e];
    qv[e*4]=t4[0]; qv[e*4+1]=t4[1]; qv[e*4+2]=t4[2]; qv[e*4+3]=t4[3];
  }
  float sv[16];
  #pragma unroll
  for (int mi=0;mi<16;++mi){
    const float* krow = kbase + (size_t)(qd*16+mi)*64;
    float a = 0.f;
    #pragma unroll
    for (int e=0;e<16;++e){
      f32x4 k4 = ((const f32x4*)krow)[e];
      a += qv[e*4]*k4[0] + qv[e*4+1]*k4[1] + qv[e*4+2]*k4[2] + qv[e*4+3]*k4[3];
    }
    sv[mi] = a*0.125f;
  }
  float mx = sv[0];
  #pragma unroll
  for (int mi=1;mi<16;++mi) mx = fmaxf(mx, sv[mi]);
  mx = fmaxf(mx, __shfl_xor(mx,1)); mx = fmaxf(mx, __shfl_xor(mx,2));
  float sum = 0.f;
  #pragma unroll
  for (int mi=0;mi<16;++mi){ sv[mi] = __expf(sv[mi]-mx); sum += sv[mi]; }
  sum += __shfl_xor(sum,1); sum += __shfl_xor(sum,2);
  float sinv = 1.f/sum;
  #pragma unroll
  for (int mi=0;mi<16;++mi){
    int m = qd*16+mi;
    float p = sv[mi]*sinv;
    if (m == r) p += 1e-4f;
    M[r*68+m] = p;
  }
  #pragma unroll
  for (int q=0;q<4;++q){
    int c = qd*16 + q*4;
    f32x4 a = {};
    #pragma unroll
    for (int kb=0;kb<8;++kb)
      a += *(const f32x4*)&t1p[((size_t)(kb*NBH + bh)*NM + r)*ND + c];
    *(f32x4*)&T[r*68+c] = a;
  }
  __syncthreads();
  for (int kp=0; kp<64; ++kp){
    if (tid < 64){
      float val = (tid >= kp) ? fabsf(M[tid*68+kp]) : -1.f;
      int idx = tid;
      #pragma unroll
      for (int off=32; off; off>>=1){
        float ov = __shfl_xor(val, off); int oi = __shfl_xor(idx, off);
        if (ov > val || (ov == val && oi < idx)){ val = ov; idx = oi; }
      }
      if (tid == 0) piv_s = idx;
    }
    __syncthreads();
    int p = piv_s;
    if (r == kp){
      float pinv = 1.f / M[p*68+kp];
      f32x4 mk[4], mp[4], tk[4], tp_[4];
      #pragma unroll
      for (int q=0;q<4;++q){
        int c = qd*16 + q*4;
        mk[q] = *(const f32x4*)&M[kp*68+c]; mp[q] = *(const f32x4*)&M[p*68+c];
        tk[q] = *(const f32x4*)&T[kp*68+c]; tp_[q] = *(const f32x4*)&T[p*68+c];
      }
      #pragma unroll
      for (int q=0;q<4;++q){
        int c = qd*16 + q*4;
        *(f32x4*)&M[p*68+c] = mk[q];       *(f32x4*)&T[p*68+c] = tk[q];
        *(f32x4*)&M[kp*68+c] = mp[q]*pinv; *(f32x4*)&T[kp*68+c] = tp_[q]*pinv;
      }
    }
    __syncthreads();
    if (r != kp){
      float f = M[r*68+kp];
      #pragma unroll
      for (int q=0;q<4;++q){
        int c = qd*16 + q*4;
        f32x4 pm = *(const f32x4*)&M[kp*68+c];
        f32x4 om = *(const f32x4*)&M[r*68+c];
        *(f32x4*)&M[r*68+c] = om - f*pm;
        f32x4 pt = *(const f32x4*)&T[kp*68+c];
        f32x4 ot = *(const f32x4*)&T[r*68+c];
        *(f32x4*)&T[r*68+c] = ot - f*pt;
      }
    }
    __syncthreads();
  }
  int d = tid>>2, qs = tid&3;
  #pragma unroll
  for (int li=0; li<16; ++li){
    int l = qs*16 + li;
    float xv = T[l*68 + d];
    u16 hb, lb; split2(xv, hb, lb);
    size_t o = ((size_t)bh*ND + d)*NM + l;
    w2th[o] = hb; w2tl[o] = lb;
  }
}

// ---------------- final: P1 = softmax(q@k_lm^T*scale); h = P1 @ w2 -> pair ----------------
__global__ __launch_bounds__(256) void k_final(const u16* __restrict__ qh, const u16* __restrict__ ql,
                                               const u16* __restrict__ klmh, const u16* __restrict__ klml,
                                               const u16* __restrict__ w2th, const u16* __restrict__ w2tl,
                                               u16* __restrict__ Hh, u16* __restrict__ Hl){
  __shared__ u16 Ph[4*4096], Pl[4*4096];
  int chunk = blockIdx.x, bh = blockIdx.y;
  int b_ = bh/NH, hd = bh - b_*NH;
  int tid = threadIdx.x, wave = tid>>6, lane = tid&63;
  int n0 = chunk*256 + wave*64;
  const u16* qhp = qh + ((size_t)bh*NSEQ + n0)*ND;
  const u16* qlp = ql + ((size_t)bh*NSEQ + n0)*ND;
  const u16* Kh = klmh + (size_t)bh*NM*ND;
  const u16* Kl = klml + (size_t)bh*NM*ND;
  const u16* Wh = w2th + (size_t)bh*ND*NM;
  const u16* Wl = w2tl + (size_t)bh*ND*NM;
  u16* Phw = Ph + wave*4096;
  u16* Plw = Pl + wave*4096;
  f32x4 accs[4][4] = {};
  #pragma unroll
  for (int kk=0; kk<2; ++kk){
    int koff = kk*32 + (lane>>4)*8;
    bf16x8 a_h[4], a_l[4], b_h[4], b_l[4];
    #pragma unroll
    for (int i=0;i<4;++i){
      size_t ro = (size_t)(i*16+(lane&15))*ND + koff;
      a_h[i] = *(const bf16x8*)&qhp[ro]; a_l[i] = *(const bf16x8*)&qlp[ro];
    }
    #pragma unroll
    for (int j=0;j<4;++j){
      size_t ro = (size_t)(j*16+(lane&15))*ND + koff;
      b_h[j] = *(const bf16x8*)&Kh[ro]; b_l[j] = *(const bf16x8*)&Kl[ro];
    }
    #pragma unroll
    for (int i=0;i<4;++i)
      #pragma unroll
      for (int j=0;j<4;++j){
        accs[i][j] = mfma16x16(a_h[i], b_h[j], accs[i][j]);
        accs[i][j] = mfma16x16(a_h[i], b_l[j], accs[i][j]);
        accs[i][j] = mfma16x16(a_l[i], b_h[j], accs[i][j]);
      }
  }
  #pragma unroll
  for (int i=0;i<4;++i)
    #pragma unroll
    for (int j=0;j<4;++j) accs[i][j] *= 0.125f;
  int rb = (lane>>4)*4, cb = lane&15;
  #pragma unroll
  for (int i=0;i<4;++i){
    #pragma unroll
    for (int r=0;r<4;++r){
      float mx = -1e30f;
      #pragma unroll
      for (int j=0;j<4;++j) mx = fmaxf(mx, accs[i][j][r]);
      #pragma unroll
      for (int off=1; off<16; off<<=1) mx = fmaxf(mx, __shfl_xor(mx, off));
      float e[4]; float sum = 0.f;
      #pragma unroll
      for (int j=0;j<4;++j){ e[j] = __expf(accs[i][j][r]-mx); sum += e[j]; }
      #pragma unroll
      for (int off=1; off<16; off<<=1) sum += __shfl_xor(sum, off);
      float inv = 1.f/sum;
      int row = i*16 + rb + r;
      #pragma unroll
      for (int j=0;j<4;++j){
        u16 hb, lb; split2(e[j]*inv, hb, lb);
        int col = j*16 + cb;
        int scol = (((col>>3) ^ (row&7))<<3) | (col&7);   // swizzled P store
        Phw[row*64 + scol] = hb;
        Plw[row*64 + scol] = lb;
      }
    }
  }
  __syncthreads();
  f32x4 acco[4][4] = {};
  #pragma unroll
  for (int kk=0; kk<2; ++kk){
    int koff = kk*32 + (lane>>4)*8;
    int sl = ((kk*4 + (lane>>4)) ^ (lane&7))*8;           // swizzled P read
    bf16x8 a_h[4], a_l[4], b_h[4], b_l[4];
    #pragma unroll
    for (int i=0;i<4;++i){
      int ro = (i*16+(lane&15))*64 + sl;
      a_h[i] = *(const bf16x8*)&Phw[ro]; a_l[i] = *(const bf16x8*)&Plw[ro];
    }
    #pragma unroll
    for (int j=0;j<4;++j){
      size_t ro = (size_t)(j*16+(lane&15))*64 + koff;
      b_h[j] = *(const bf16x8*)&Wh[ro]; b_l[j] = *(const bf16x8*)&Wl[ro];
    }
    #pragma unroll
    for (int i=0;i<4;++i)
      #pragma unroll
      for (int j=0;j<4;++j){
        acco[i][j] = mfma16x16(a_h[i], b_h[j], acco[i][j]);
        acco[i][j] = mfma16x16(a_h[i], b_l[j], acco[i][j]);
        acco[i][j] = mfma16x16(a_l[i], b_h[j], acco[i][j]);
      }
  }
  #pragma unroll
  for (int i=0;i<4;++i)
    #pragma unroll
    for (int j=0;j<4;++j)
      #pragma unroll
      for (int r=0;r<4;++r){
        int n = n0 + i*16 + rb + r;
        int d = j*16 + cb;
        size_t o = ((size_t)(b_*NSEQ + n))*NC + hd*64 + d;
        u16 hb, lb; split2(acco[i][j][r], hb, lb);
        Hh[o] = hb; Hl[o] = lb;
      }
}

__global__ void k_sent(float* out){ out[0] = 1.0e9f; }

// ---------------- workspace layout (bytes) ----------------
#define OFF_QH     0ull
#define OFF_QL     25165824ull
#define OFF_KH     50331648ull
#define OFF_KL     75497472ull
#define OFF_VTH    100663296ull   /* v written directly transposed by k_qkv8 */
#define OFF_VTL    125829120ull
#define OFF_S2     150994944ull   /* xh/xl during split+qkv; s2f f32; Hh/Hl after k_t1 */
#define OFF_QLMF   201326592ull
#define OFF_KLMF   202113024ull
#define OFF_QLMH   202899456ull
#define OFF_QLML   203292672ull
#define OFF_KLMH   203685888ull
#define OFF_KLML   204079104ull
#define OFF_W2TH   204472320ull
#define OFF_W2TL   204865536ull
#define OFF_T1P    205258752ull
#define OFF_WQH    211550208ull   /* wqkv-hi during split+qkv; softmax stats after (1.5 MB) */
#define OFF_WQL    215089152ull
#define OFF_WPH    218628096ull
#define OFF_WPL    219807744ull
#define WS_NEEDED  220987392ull

extern "C" void kernel_launch(void* const* d_in, const int* in_sizes, int n_in,
                              void* d_out, int out_size, void* d_ws, size_t ws_size,
                              hipStream_t stream){
  const float* x     = (const float*)d_in[0];
  const float* wqkv  = (const float*)d_in[1];
  const float* wproj = (const float*)d_in[2];
  const float* bproj = (const float*)d_in[3];
  float* out = (float*)d_out;
  char* ws = (char*)d_ws;
  if (ws_size < WS_NEEDED){ k_sent<<<1,1,0,stream>>>(out); return; }
  u16* qh = (u16*)(ws + OFF_QH);  u16* ql = (u16*)(ws + OFF_QL);
  u16* kh = (u16*)(ws + OFF_KH);  u16* kl = (u16*)(ws + OFF_KL);
  u16* vTh = (u16*)(ws + OFF_VTH); u16* vTl = (u16*)(ws + OFF_VTL);
  u16* xh = (u16*)(ws + OFF_S2);                // alias: S2 region during split+qkv
  u16* xl = (u16*)(ws + OFF_S2 + 25165824ull);
  float* s2f = (float*)(ws + OFF_S2);
  u16* Hh = (u16*)(ws + OFF_S2);                // alias: h pair after s2f dead (post k_t1)
  u16* Hl = (u16*)(ws + OFF_S2 + 25165824ull);
  float* qlmf = (float*)(ws + OFF_QLMF);
  float* klmf = (float*)(ws + OFF_KLMF);
  u16* qlmh = (u16*)(ws + OFF_QLMH); u16* qlml = (u16*)(ws + OFF_QLML);
  u16* klmh = (u16*)(ws + OFF_KLMH); u16* klml = (u16*)(ws + OFF_KLML);
  u16* w2th = (u16*)(ws + OFF_W2TH); u16* w2tl = (u16*)(ws + OFF_W2TL);
  float* t1p = (float*)(ws + OFF_T1P);
  u16* wqh = (u16*)(ws + OFF_WQH); u16* wql = (u16*)(ws + OFF_WQL);
  u16* wph = (u16*)(ws + OFF_WPH); u16* wpl = (u16*)(ws + OFF_WPL);
  float* stats = (float*)(ws + OFF_WQH);        // alias: wqh dead after k_qkv8 (1.5 MB used)

  k_split3   <<<14592, 256, 0, stream>>>(x, wqkv, wproj, xh, xl, wqh, wql, wph, wpl);
  k_qkv8     <<<576, 512, 0, stream>>>(xh, xl, wqh, wql, qh, ql, kh, kl, vTh, vTl,
                                       qlmf, klmf, qlmh, qlml, klmh, klml);
  k_s2       <<<dim3(16,48),  256, 0, stream>>>(qlmh, qlml, kh, kl, s2f, stats);
  k_t1       <<<dim3(8,48),   256, 0, stream>>>(s2f, stats, vTh, vTl, t1p);
  k_mid      <<<48,           256, 0, stream>>>(qlmf, klmf, t1p, w2th, w2tl);
  k_final    <<<dim3(16,48),  256, 0, stream>>>(qh, ql, klmh, klml, w2th, w2tl, Hh, Hl);
  k_proj     <<<768,          256, 0, stream>>>(Hh, Hl, wph, wpl, bproj, out);
}

// Round 12
// 494.938 us; speedup vs baseline: 1.1840x; 1.1840x over previous
//
#include <hip/hip_runtime.h>

typedef unsigned short u16;
typedef __attribute__((ext_vector_type(8))) short bf16x8;
typedef __attribute__((ext_vector_type(8))) unsigned short u16x8;
typedef __attribute__((ext_vector_type(4))) unsigned short u16x4;
typedef __attribute__((ext_vector_type(4))) float f32x4;

#define NB 4
#define NH 12
#define NSEQ 4096
#define NC 768
#define ND 64
#define NM 64
#define NBH 48

__device__ __forceinline__ float b2f(u16 u){ unsigned v = ((unsigned)u)<<16; return __builtin_bit_cast(float, v); }
__device__ __forceinline__ u16 f2b(float f){ unsigned u = __builtin_bit_cast(unsigned, f); u = u + 0x7FFFu + ((u>>16)&1u); return (u16)(u>>16); }
__device__ __forceinline__ void split2(float f, u16& h, u16& l){
  h = f2b(f);
  l = f2b(f - b2f(h));
}

typedef const __attribute__((address_space(1))) unsigned int guint;
typedef __attribute__((address_space(3))) unsigned int luint;
__device__ __forceinline__ void gload16(const void* g, void* l){
  __builtin_amdgcn_global_load_lds((guint*)g, (luint*)l, 16, 0, 0);
}

__device__ __forceinline__ f32x4 mfma16x16(bf16x8 a, bf16x8 b, f32x4 c){
  return __builtin_amdgcn_mfma_f32_16x16x32_bf16(a, b, c, 0, 0, 0);
}

// ---------------- merged split: f32 -> (hi,lo) bf16 pairs for x, wqkv, wproj ----------------
#define NX4 3145728
#define NWQ4 442368
#define NWP4 147456
__global__ __launch_bounds__(256) void k_split3(const float* __restrict__ x, const float* __restrict__ wq,
                                                const float* __restrict__ wp,
                                                u16* __restrict__ xh, u16* __restrict__ xl,
                                                u16* __restrict__ wqh, u16* __restrict__ wql,
                                                u16* __restrict__ wph, u16* __restrict__ wpl){
  int i = blockIdx.x*256 + threadIdx.x;
  const float* src; u16 *dh, *dl; int j;
  if (i < NX4){ src = x; dh = xh; dl = xl; j = i; }
  else if (i < NX4+NWQ4){ src = wq; dh = wqh; dl = wql; j = i - NX4; }
  else if (i < NX4+NWQ4+NWP4){ src = wp; dh = wph; dl = wpl; j = i - NX4 - NWQ4; }
  else return;
  f32x4 v = ((const f32x4*)src)[j];
  u16x4 hh, ll;
  #pragma unroll
  for (int e=0;e<4;++e){ u16 hb, lb; split2(v[e], hb, lb); hh[e]=hb; ll[e]=lb; }
  ((u16x4*)dh)[j] = hh; ((u16x4*)dl)[j] = ll;
}

// ============ 128x128 BK=64 split-bf16 GEMM, T2-swizzled LDS (0-conflict), XCD-swizzled grid ====

// ---------------- big GEMM 1: qkv = X @ Wqkv^T; q/k row-major + fused pooling; v transposed ----------------
__global__ __launch_bounds__(256) void k_qkv(const u16* __restrict__ xh, const u16* __restrict__ xl,
                                             const u16* __restrict__ wh, const u16* __restrict__ wl,
                                             u16* __restrict__ qh, u16* __restrict__ ql,
                                             u16* __restrict__ kh, u16* __restrict__ kl,
                                             u16* __restrict__ vTh, u16* __restrict__ vTl,
                                             float* __restrict__ qlmf, float* __restrict__ klmf,
                                             u16* __restrict__ qlmh, u16* __restrict__ qlml,
                                             u16* __restrict__ klmh, u16* __restrict__ klml){
  __shared__ u16 lds[32768];   // 64 KB: Ah | Al | Bh | Bl (8192 u16 each)
  const int K = NC;
  int tid = threadIdx.x, wave = tid>>6, lane = tid&63;
  int wm = wave>>1, wn = wave&1;
  int bid = blockIdx.x;                    // 2304 blocks, %8==0
  int swz = (bid&7)*288 + (bid>>3);        // bijective XCD swizzle
  int bx = swz % 18, by = swz / 18;        // n-fastest within XCD chunk -> A-panel locality
  int m0 = by*128, n0 = bx*128;
  int srow = lane>>3;
  int scol = ((lane&7) ^ srow)*8;          // pre-swizzled global column
  const u16* src0; u16* dst0;
  if (wave==0){ src0 = xh + (size_t)m0*K; dst0 = lds; }
  else if (wave==1){ src0 = xl + (size_t)m0*K; dst0 = lds+8192; }
  else if (wave==2){ src0 = wh + (size_t)n0*K; dst0 = lds+16384; }
  else            { src0 = wl + (size_t)n0*K; dst0 = lds+24576; }
  f32x4 acc[4][4] = {};
  for (int k0=0; k0<K; k0+=64){
    #pragma unroll
    for (int it=0; it<16; ++it){
      int r = it*8;
      gload16(&src0[(size_t)(r+srow)*K + k0 + scol], &dst0[r*64]);
    }
    __syncthreads();
    #pragma unroll
    for (int kk=0; kk<2; ++kk){
      int sl = ((kk*4 + (lane>>4)) ^ (lane&7))*8;   // swizzled read slot
      bf16x8 a_h[4], a_l[4], b_h[4], b_l[4];
      #pragma unroll
      for (int i=0;i<4;++i){
        int ro = (wm*64+i*16+(lane&15))*64 + sl;
        a_h[i] = *(const bf16x8*)&lds[ro]; a_l[i] = *(const bf16x8*)&lds[8192+ro];
      }
      #pragma unroll
      for (int j=0;j<4;++j){
        int ro = (wn*64+j*16+(lane&15))*64 + sl;
        b_h[j] = *(const bf16x8*)&lds[16384+ro]; b_l[j] = *(const bf16x8*)&lds[24576+ro];
      }
      #pragma unroll
      for (int i=0;i<4;++i)
        #pragma unroll
        for (int j=0;j<4;++j){
          acc[i][j] = mfma16x16(a_h[i], b_h[j], acc[i][j]);
          acc[i][j] = mfma16x16(a_h[i], b_l[j], acc[i][j]);
          acc[i][j] = mfma16x16(a_l[i], b_h[j], acc[i][j]);
        }
    }
    __syncthreads();
  }
  int rb = (lane>>4)*4, cb = lane&15;
  int b_ = m0>>12, nlo = m0&4095;
  if (n0 < 1536){
    // ---- q or k block: row-major stores + fused segment pooling ----
    int s = n0/768;
    u16* dh = s ? kh : qh;
    u16* dl = s ? kl : ql;
    float* lmf = s ? klmf : qlmf;
    u16* lmh = s ? klmh : qlmh;
    u16* lml = s ? klml : qlml;
    #pragma unroll
    for (int j=0;j<4;++j){
      int gn = n0 + wn*64 + j*16 + cb;
      int rem = gn - s*768; int hd = rem>>6, d = rem&63;
      #pragma unroll
      for (int i=0;i<4;++i)
        #pragma unroll
        for (int r=0;r<4;++r){
          int n = nlo + wm*64 + i*16 + rb + r;
          size_t idx = (((size_t)(b_*NH + hd))*NSEQ + n)*ND + d;
          u16 hb, lb; split2(acc[i][j][r], hb, lb);
          dh[idx] = hb; dl[idx] = lb;
        }
      float tot = 0.f;
      #pragma unroll
      for (int i=0;i<4;++i)
        #pragma unroll
        for (int r=0;r<4;++r) tot += acc[i][j][r];
      tot += __shfl_xor(tot, 16);
      tot += __shfl_xor(tot, 32);
      if (lane < 16){
        int lseg = (nlo>>6) + wm;
        float mean = tot * (1.f/64.f);
        size_t o = (((size_t)(b_*NH + hd))*NM + lseg)*ND + d;
        lmf[o] = mean;
        u16 hb, lb; split2(mean, hb, lb);
        lmh[o] = hb; lml[o] = lb;
      }
    }
  } else {
    // ---- v block: transpose 128x128 tile via LDS, coalesced vT writes ----
    const int TS = 136;
    #pragma unroll
    for (int part=0; part<2; ++part){
      __syncthreads();
      #pragma unroll
      for (int j=0;j<4;++j){
        int dcol = wn*64 + j*16 + cb;
        #pragma unroll
        for (int i=0;i<4;++i)
          #pragma unroll
          for (int r=0;r<4;++r){
            int nrow = wm*64 + i*16 + rb + r;
            u16 hb, lb; split2(acc[i][j][r], hb, lb);
            lds[dcol*TS + nrow] = part ? lb : hb;
          }
      }
      __syncthreads();
      int drow = tid>>1, half = (tid&1)*64;
      int remd = (n0 - 1536) + drow;
      int hd = remd>>6, dd = remd&63;
      u16* dst = (part ? vTl : vTh) + (((size_t)(b_*NH + hd))*ND + dd)*NSEQ + nlo + half;
      const u16* srcl = &lds[drow*TS + half];
      #pragma unroll
      for (int e=0;e<8;++e)
        *(u16x8*)(dst + e*8) = *(const u16x8*)(srcl + e*8);
    }
  }
}

// ---------------- big GEMM 2: out = H @ Wproj^T + bias (f32 out) ----------------
__global__ __launch_bounds__(256) void k_proj(const u16* __restrict__ Hh, const u16* __restrict__ Hl,
                                              const u16* __restrict__ wh, const u16* __restrict__ wl,
                                              const float* __restrict__ bias, float* __restrict__ out){
  __shared__ u16 lds[32768];
  const int K = NC;
  int tid = threadIdx.x, wave = tid>>6, lane = tid&63;
  int wm = wave>>1, wn = wave&1;
  int bid = blockIdx.x;                    // 768 blocks, %8==0
  int swz = (bid&7)*96 + (bid>>3);
  int bx = swz % 6, by = swz / 6;
  int m0 = by*128, n0 = bx*128;
  int srow = lane>>3;
  int scol = ((lane&7) ^ srow)*8;
  const u16* src0; u16* dst0;
  if (wave==0){ src0 = Hh + (size_t)m0*K; dst0 = lds; }
  else if (wave==1){ src0 = Hl + (size_t)m0*K; dst0 = lds+8192; }
  else if (wave==2){ src0 = wh + (size_t)n0*K; dst0 = lds+16384; }
  else            { src0 = wl + (size_t)n0*K; dst0 = lds+24576; }
  f32x4 acc[4][4] = {};
  for (int k0=0; k0<K; k0+=64){
    #pragma unroll
    for (int it=0; it<16; ++it){
      int r = it*8;
      gload16(&src0[(size_t)(r+srow)*K + k0 + scol], &dst0[r*64]);
    }
    __syncthreads();
    #pragma unroll
    for (int kk=0; kk<2; ++kk){
      int sl = ((kk*4 + (lane>>4)) ^ (lane&7))*8;
      bf16x8 a_h[4], a_l[4], b_h[4], b_l[4];
      #pragma unroll
      for (int i=0;i<4;++i){
        int ro = (wm*64+i*16+(lane&15))*64 + sl;
        a_h[i] = *(const bf16x8*)&lds[ro]; a_l[i] = *(const bf16x8*)&lds[8192+ro];
      }
      #pragma unroll
      for (int j=0;j<4;++j){
        int ro = (wn*64+j*16+(lane&15))*64 + sl;
        b_h[j] = *(const bf16x8*)&lds[16384+ro]; b_l[j] = *(const bf16x8*)&lds[24576+ro];
      }
      #pragma unroll
      for (int i=0;i<4;++i)
        #pragma unroll
        for (int j=0;j<4;++j){
          acc[i][j] = mfma16x16(a_h[i], b_h[j], acc[i][j]);
          acc[i][j] = mfma16x16(a_h[i], b_l[j], acc[i][j]);
          acc[i][j] = mfma16x16(a_l[i], b_h[j], acc[i][j]);
        }
    }
    __syncthreads();
  }
  int rb = (lane>>4)*4, cb = lane&15;
  #pragma unroll
  for (int j=0;j<4;++j){
    int gn = n0 + wn*64 + j*16 + cb;
    float bb = bias[gn];
    #pragma unroll
    for (int i=0;i<4;++i){
      #pragma unroll
      for (int r=0;r<4;++r){
        int gm = m0 + wm*64 + i*16 + rb + r;
        out[(size_t)gm*NC + gn] = acc[i][j][r] + bb;
      }
    }
  }
}

// ---------------- s2 = q_lm @ k^T * scale -> f32 [BH][64][4096], + per-block softmax partials ----------------
__global__ __launch_bounds__(256) void k_s2(const u16* __restrict__ qlmh, const u16* __restrict__ qlml,
                                            const u16* __restrict__ kh, const u16* __restrict__ kl,
                                            float* __restrict__ s2f, float* __restrict__ stats){
  int chunk = blockIdx.x, bh = blockIdx.y;
  int tid = threadIdx.x, wave = tid>>6, lane = tid&63;
  const u16* Ahp = qlmh + (size_t)bh*NM*ND;
  const u16* Alp = qlml + (size_t)bh*NM*ND;
  const u16* Bhp = kh + (size_t)bh*NSEQ*ND;
  const u16* Blp = kl + (size_t)bh*NSEQ*ND;
  int nbase = chunk*256 + wave*64;
  f32x4 acc[4][4] = {};
  #pragma unroll
  for (int kk=0; kk<2; ++kk){
    int koff = kk*32 + (lane>>4)*8;
    bf16x8 a_h[4], a_l[4], b_h[4], b_l[4];
    #pragma unroll
    for (int i=0;i<4;++i){
      size_t ro = (size_t)(i*16+(lane&15))*ND + koff;
      a_h[i] = *(const bf16x8*)&Ahp[ro]; a_l[i] = *(const bf16x8*)&Alp[ro];
    }
    #pragma unroll
    for (int j=0;j<4;++j){
      size_t ro = (size_t)(nbase + j*16 + (lane&15))*ND + koff;
      b_h[j] = *(const bf16x8*)&Bhp[ro]; b_l[j] = *(const bf16x8*)&Blp[ro];
    }
    #pragma unroll
    for (int i=0;i<4;++i)
      #pragma unroll
      for (int j=0;j<4;++j){
        acc[i][j] = mfma16x16(a_h[i], b_h[j], acc[i][j]);
        acc[i][j] = mfma16x16(a_h[i], b_l[j], acc[i][j]);
        acc[i][j] = mfma16x16(a_l[i], b_h[j], acc[i][j]);
      }
  }
  int rb = (lane>>4)*4, cb = lane&15;
  #pragma unroll
  for (int i=0;i<4;++i)
    #pragma unroll
    for (int j=0;j<4;++j)
      #pragma unroll
      for (int r=0;r<4;++r){
        int l = i*16 + rb + r; int n = nbase + j*16 + cb;
        s2f[((size_t)bh*NM + l)*NSEQ + n] = acc[i][j][r]*0.125f;
      }
  #pragma unroll
  for (int i=0;i<4;++i)
    #pragma unroll
    for (int r=0;r<4;++r){
      float v0 = acc[i][0][r]*0.125f, v1 = acc[i][1][r]*0.125f;
      float v2 = acc[i][2][r]*0.125f, v3 = acc[i][3][r]*0.125f;
      float mx = fmaxf(fmaxf(v0,v1), fmaxf(v2,v3));
      #pragma unroll
      for (int off=1; off<16; off<<=1) mx = fmaxf(mx, __shfl_xor(mx, off));
      float se = __expf(v0-mx)+__expf(v1-mx)+__expf(v2-mx)+__expf(v3-mx);
      #pragma unroll
      for (int off=1; off<16; off<<=1) se += __shfl_xor(se, off);
      if (cb == 0){
        int row = i*16 + rb + r;
        size_t o = ((((size_t)chunk*NBH + bh)*4 + wave)*64 + row)*2;
        stats[o] = mx; stats[o+1] = se;
      }
    }
}

// ---------------- t1 partials with inline softmax ----------------
__global__ __launch_bounds__(256) void k_t1(const float* __restrict__ s2f, const float* __restrict__ stats,
                                            const u16* __restrict__ vTh, const u16* __restrict__ vTl,
                                            float* __restrict__ t1p){
  int kb = blockIdx.x, bh = blockIdx.y;
  int tid = threadIdx.x, wave = tid>>6, lane = tid&63;
  int arow = wave*16 + (lane&15);
  float MX = -1e30f;
  for (int c=0;c<16;++c)
    #pragma unroll
    for (int w=0;w<4;++w)
      MX = fmaxf(MX, stats[((((size_t)c*NBH + bh)*4 + w)*64 + arow)*2]);
  float SE = 0.f;
  for (int c=0;c<16;++c)
    #pragma unroll
    for (int w=0;w<4;++w){
      size_t o = ((((size_t)c*NBH + bh)*4 + w)*64 + arow)*2;
      SE += stats[o+1]*__expf(stats[o]-MX);
    }
  float INV = 1.f/SE;
  const float* srow = s2f + ((size_t)bh*NM + arow)*NSEQ;
  const u16* Bh = vTh + (size_t)bh*ND*NSEQ;
  const u16* Bl = vTl + (size_t)bh*ND*NSEQ;
  f32x4 acc[4] = {};
  for (int ks=0; ks<16; ++ks){
    int koff = kb*512 + ks*32 + (lane>>4)*8;
    f32x4 sv0 = *(const f32x4*)&srow[koff];
    f32x4 sv1 = *(const f32x4*)&srow[koff+4];
    bf16x8 a_h, a_l;
    #pragma unroll
    for (int e=0;e<4;++e){
      u16 hb, lb;
      split2(__expf(sv0[e]-MX)*INV, hb, lb); a_h[e]   = (short)hb; a_l[e]   = (short)lb;
      split2(__expf(sv1[e]-MX)*INV, hb, lb); a_h[4+e] = (short)hb; a_l[4+e] = (short)lb;
    }
    #pragma unroll
    for (int j=0;j<4;++j){
      size_t ro = (size_t)(j*16+(lane&15))*NSEQ + koff;
      bf16x8 b_h = *(const bf16x8*)&Bh[ro];
      bf16x8 b_l = *(const bf16x8*)&Bl[ro];
      acc[j] = mfma16x16(a_h, b_h, acc[j]);
      acc[j] = mfma16x16(a_h, b_l, acc[j]);
      acc[j] = mfma16x16(a_l, b_h, acc[j]);
    }
  }
  int rb = (lane>>4)*4, cb = lane&15;
  #pragma unroll
  for (int j=0;j<4;++j)
    #pragma unroll
    for (int r=0;r<4;++r){
      int l = wave*16 + rb + r; int d = j*16 + cb;
      t1p[((size_t)(kb*NBH + bh)*NM + l)*ND + d] = acc[j][r];
    }
}

// ---------------- mid (4-wave): Gram+softmax -> M; T = sum t1p; GJ solve [M|T] -> X; write X^T pair
__global__ __launch_bounds__(256) void k_mid(const float* __restrict__ qlmf, const float* __restrict__ klmf,
                                            const float* __restrict__ t1p,
                                            u16* __restrict__ w2th, u16* __restrict__ w2tl){
  __shared__ float M[64*68];
  __shared__ float T[64*68];
  __shared__ int piv_s;
  int bh = blockIdx.x, tid = threadIdx.x;
  int r = tid>>2, qd = tid&3;           // row, 16-col quad
  const float* qrow  = qlmf + (size_t)bh*NM*ND + r*64;
  const float* kbase = klmf + (size_t)bh*NM*ND;
  float qv[64];
  #pragma unroll
  for (int e=0;e<16;++e){
    f32x4 t4 = ((const f32x4*)qrow)[e];
    qv[e*4]=t4[0]; qv[e*4+1]=t4[1]; qv[e*4+2]=t4[2]; qv[e*4+3]=t4[3];
  }
  float sv[16];
  #pragma unroll
  for (int mi=0;mi<16;++mi){
    const float* krow = kbase + (size_t)(qd*16+mi)*64;
    float a = 0.f;
    #pragma unroll
    for (int e=0;e<16;++e){
      f32x4 k4 = ((const f32x4*)krow)[e];
      a += qv[e*4]*k4[0] + qv[e*4+1]*k4[1] + qv[e*4+2]*k4[2] + qv[e*4+3]*k4[3];
    }
    sv[mi] = a*0.125f;
  }
  float mx = sv[0];
  #pragma unroll
  for (int mi=1;mi<16;++mi) mx = fmaxf(mx, sv[mi]);
  mx = fmaxf(mx, __shfl_xor(mx,1)); mx = fmaxf(mx, __shfl_xor(mx,2));
  float sum = 0.f;
  #pragma unroll
  for (int mi=0;mi<16;++mi){ sv[mi] = __expf(sv[mi]-mx); sum += sv[mi]; }
  sum += __shfl_xor(sum,1); sum += __shfl_xor(sum,2);
  float sinv = 1.f/sum;
  #pragma unroll
  for (int mi=0;mi<16;++mi){
    int m = qd*16+mi;
    float p = sv[mi]*sinv;
    if (m == r) p += 1e-4f;
    M[r*68+m] = p;
  }
  #pragma unroll
  for (int q=0;q<4;++q){
    int c = qd*16 + q*4;
    f32x4 a = {};
    #pragma unroll
    for (int kb=0;kb<8;++kb)
      a += *(const f32x4*)&t1p[((size_t)(kb*NBH + bh)*NM + r)*ND + c];
    *(f32x4*)&T[r*68+c] = a;
  }
  __syncthreads();
  for (int kp=0; kp<64; ++kp){
    if (tid < 64){
      float val = (tid >= kp) ? fabsf(M[tid*68+kp]) : -1.f;
      int idx = tid;
      #pragma unroll
      for (int off=32; off; off>>=1){
        float ov = __shfl_xor(val, off); int oi = __shfl_xor(idx, off);
        if (ov > val || (ov == val && oi < idx)){ val = ov; idx = oi; }
      }
      if (tid == 0) piv_s = idx;
    }
    __syncthreads();
    int p = piv_s;
    if (r == kp){
      float pinv = 1.f / M[p*68+kp];
      f32x4 mk[4], mp[4], tk[4], tp_[4];
      #pragma unroll
      for (int q=0;q<4;++q){
        int c = qd*16 + q*4;
        mk[q] = *(const f32x4*)&M[kp*68+c]; mp[q] = *(const f32x4*)&M[p*68+c];
        tk[q] = *(const f32x4*)&T[kp*68+c]; tp_[q] = *(const f32x4*)&T[p*68+c];
      }
      #pragma unroll
      for (int q=0;q<4;++q){
        int c = qd*16 + q*4;
        *(f32x4*)&M[p*68+c] = mk[q];       *(f32x4*)&T[p*68+c] = tk[q];
        *(f32x4*)&M[kp*68+c] = mp[q]*pinv; *(f32x4*)&T[kp*68+c] = tp_[q]*pinv;
      }
    }
    __syncthreads();
    if (r != kp){
      float f = M[r*68+kp];
      #pragma unroll
      for (int q=0;q<4;++q){
        int c = qd*16 + q*4;
        f32x4 pm = *(const f32x4*)&M[kp*68+c];
        f32x4 om = *(const f32x4*)&M[r*68+c];
        *(f32x4*)&M[r*68+c] = om - f*pm;
        f32x4 pt = *(const f32x4*)&T[kp*68+c];
        f32x4 ot = *(const f32x4*)&T[r*68+c];
        *(f32x4*)&T[r*68+c] = ot - f*pt;
      }
    }
    __syncthreads();
  }
  int d = tid>>2, qs = tid&3;
  #pragma unroll
  for (int li=0; li<16; ++li){
    int l = qs*16 + li;
    float xv = T[l*68 + d];
    u16 hb, lb; split2(xv, hb, lb);
    size_t o = ((size_t)bh*ND + d)*NM + l;
    w2th[o] = hb; w2tl[o] = lb;
  }
}

// ---------------- final: P1 = softmax(q@k_lm^T*scale); h = P1 @ w2 -> pair ----------------
__global__ __launch_bounds__(256) void k_final(const u16* __restrict__ qh, const u16* __restrict__ ql,
                                               const u16* __restrict__ klmh, const u16* __restrict__ klml,
                                               const u16* __restrict__ w2th, const u16* __restrict__ w2tl,
                                               u16* __restrict__ Hh, u16* __restrict__ Hl){
  __shared__ u16 Ph[4*4096], Pl[4*4096];
  int chunk = blockIdx.x, bh = blockIdx.y;
  int b_ = bh/NH, hd = bh - b_*NH;
  int tid = threadIdx.x, wave = tid>>6, lane = tid&63;
  int n0 = chunk*256 + wave*64;
  const u16* qhp = qh + ((size_t)bh*NSEQ + n0)*ND;
  const u16* qlp = ql + ((size_t)bh*NSEQ + n0)*ND;
  const u16* Kh = klmh + (size_t)bh*NM*ND;
  const u16* Kl = klml + (size_t)bh*NM*ND;
  const u16* Wh = w2th + (size_t)bh*ND*NM;
  const u16* Wl = w2tl + (size_t)bh*ND*NM;
  u16* Phw = Ph + wave*4096;
  u16* Plw = Pl + wave*4096;
  f32x4 accs[4][4] = {};
  #pragma unroll
  for (int kk=0; kk<2; ++kk){
    int koff = kk*32 + (lane>>4)*8;
    bf16x8 a_h[4], a_l[4], b_h[4], b_l[4];
    #pragma unroll
    for (int i=0;i<4;++i){
      size_t ro = (size_t)(i*16+(lane&15))*ND + koff;
      a_h[i] = *(const bf16x8*)&qhp[ro]; a_l[i] = *(const bf16x8*)&qlp[ro];
    }
    #pragma unroll
    for (int j=0;j<4;++j){
      size_t ro = (size_t)(j*16+(lane&15))*ND + koff;
      b_h[j] = *(const bf16x8*)&Kh[ro]; b_l[j] = *(const bf16x8*)&Kl[ro];
    }
    #pragma unroll
    for (int i=0;i<4;++i)
      #pragma unroll
      for (int j=0;j<4;++j){
        accs[i][j] = mfma16x16(a_h[i], b_h[j], accs[i][j]);
        accs[i][j] = mfma16x16(a_h[i], b_l[j], accs[i][j]);
        accs[i][j] = mfma16x16(a_l[i], b_h[j], accs[i][j]);
      }
  }
  #pragma unroll
  for (int i=0;i<4;++i)
    #pragma unroll
    for (int j=0;j<4;++j) accs[i][j] *= 0.125f;
  int rb = (lane>>4)*4, cb = lane&15;
  #pragma unroll
  for (int i=0;i<4;++i){
    #pragma unroll
    for (int r=0;r<4;++r){
      float mx = -1e30f;
      #pragma unroll
      for (int j=0;j<4;++j) mx = fmaxf(mx, accs[i][j][r]);
      #pragma unroll
      for (int off=1; off<16; off<<=1) mx = fmaxf(mx, __shfl_xor(mx, off));
      float e[4]; float sum = 0.f;
      #pragma unroll
      for (int j=0;j<4;++j){ e[j] = __expf(accs[i][j][r]-mx); sum += e[j]; }
      #pragma unroll
      for (int off=1; off<16; off<<=1) sum += __shfl_xor(sum, off);
      float inv = 1.f/sum;
      int row = i*16 + rb + r;
      #pragma unroll
      for (int j=0;j<4;++j){
        u16 hb, lb; split2(e[j]*inv, hb, lb);
        int col = j*16 + cb;
        int scol = (((col>>3) ^ (row&7))<<3) | (col&7);   // swizzled P store
        Phw[row*64 + scol] = hb;
        Plw[row*64 + scol] = lb;
      }
    }
  }
  __syncthreads();
  f32x4 acco[4][4] = {};
  #pragma unroll
  for (int kk=0; kk<2; ++kk){
    int koff = kk*32 + (lane>>4)*8;
    int sl = ((kk*4 + (lane>>4)) ^ (lane&7))*8;           // swizzled P read
    bf16x8 a_h[4], a_l[4], b_h[4], b_l[4];
    #pragma unroll
    for (int i=0;i<4;++i){
      int ro = (i*16+(lane&15))*64 + sl;
      a_h[i] = *(const bf16x8*)&Phw[ro]; a_l[i] = *(const bf16x8*)&Plw[ro];
    }
    #pragma unroll
    for (int j=0;j<4;++j){
      size_t ro = (size_t)(j*16+(lane&15))*64 + koff;
      b_h[j] = *(const bf16x8*)&Wh[ro]; b_l[j] = *(const bf16x8*)&Wl[ro];
    }
    #pragma unroll
    for (int i=0;i<4;++i)
      #pragma unroll
      for (int j=0;j<4;++j){
        acco[i][j] = mfma16x16(a_h[i], b_h[j], acco[i][j]);
        acco[i][j] = mfma16x16(a_h[i], b_l[j], acco[i][j]);
        acco[i][j] = mfma16x16(a_l[i], b_h[j], acco[i][j]);
      }
  }
  #pragma unroll
  for (int i=0;i<4;++i)
    #pragma unroll
    for (int j=0;j<4;++j)
      #pragma unroll
      for (int r=0;r<4;++r){
        int n = n0 + i*16 + rb + r;
        int d = j*16 + cb;
        size_t o = ((size_t)(b_*NSEQ + n))*NC + hd*64 + d;
        u16 hb, lb; split2(acco[i][j][r], hb, lb);
        Hh[o] = hb; Hl[o] = lb;
      }
}

__global__ void k_sent(float* out){ out[0] = 1.0e9f; }

// ---------------- workspace layout (bytes) ----------------
#define OFF_QH     0ull
#define OFF_QL     25165824ull
#define OFF_KH     50331648ull
#define OFF_KL     75497472ull
#define OFF_VTH    100663296ull   /* v written directly transposed by k_qkv */
#define OFF_VTL    125829120ull
#define OFF_S2     150994944ull   /* xh/xl during split+qkv; s2f f32; Hh/Hl after k_t1 */
#define OFF_QLMF   201326592ull
#define OFF_KLMF   202113024ull
#define OFF_QLMH   202899456ull
#define OFF_QLML   203292672ull
#define OFF_KLMH   203685888ull
#define OFF_KLML   204079104ull
#define OFF_W2TH   204472320ull
#define OFF_W2TL   204865536ull
#define OFF_T1P    205258752ull
#define OFF_WQH    211550208ull   /* wqkv-hi during split+qkv; softmax stats after (1.5 MB) */
#define OFF_WQL    215089152ull
#define OFF_WPH    218628096ull
#define OFF_WPL    219807744ull
#define WS_NEEDED  220987392ull

extern "C" void kernel_launch(void* const* d_in, const int* in_sizes, int n_in,
                              void* d_out, int out_size, void* d_ws, size_t ws_size,
                              hipStream_t stream){
  const float* x     = (const float*)d_in[0];
  const float* wqkv  = (const float*)d_in[1];
  const float* wproj = (const float*)d_in[2];
  const float* bproj = (const float*)d_in[3];
  float* out = (float*)d_out;
  char* ws = (char*)d_ws;
  if (ws_size < WS_NEEDED){ k_sent<<<1,1,0,stream>>>(out); return; }
  u16* qh = (u16*)(ws + OFF_QH);  u16* ql = (u16*)(ws + OFF_QL);
  u16* kh = (u16*)(ws + OFF_KH);  u16* kl = (u16*)(ws + OFF_KL);
  u16* vTh = (u16*)(ws + OFF_VTH); u16* vTl = (u16*)(ws + OFF_VTL);
  u16* xh = (u16*)(ws + OFF_S2);                // alias: S2 region during split+qkv
  u16* xl = (u16*)(ws + OFF_S2 + 25165824ull);
  float* s2f = (float*)(ws + OFF_S2);
  u16* Hh = (u16*)(ws + OFF_S2);                // alias: h pair after s2f dead (post k_t1)
  u16* Hl = (u16*)(ws + OFF_S2 + 25165824ull);
  float* qlmf = (float*)(ws + OFF_QLMF);
  float* klmf = (float*)(ws + OFF_KLMF);
  u16* qlmh = (u16*)(ws + OFF_QLMH); u16* qlml = (u16*)(ws + OFF_QLML);
  u16* klmh = (u16*)(ws + OFF_KLMH); u16* klml = (u16*)(ws + OFF_KLML);
  u16* w2th = (u16*)(ws + OFF_W2TH); u16* w2tl = (u16*)(ws + OFF_W2TL);
  float* t1p = (float*)(ws + OFF_T1P);
  u16* wqh = (u16*)(ws + OFF_WQH); u16* wql = (u16*)(ws + OFF_WQL);
  u16* wph = (u16*)(ws + OFF_WPH); u16* wpl = (u16*)(ws + OFF_WPL);
  float* stats = (float*)(ws + OFF_WQH);        // alias: wqh dead after k_qkv (1.5 MB used)

  k_split3   <<<14592, 256, 0, stream>>>(x, wqkv, wproj, xh, xl, wqh, wql, wph, wpl);
  k_qkv      <<<2304, 256, 0, stream>>>(xh, xl, wqh, wql, qh, ql, kh, kl, vTh, vTl,
                                        qlmf, klmf, qlmh, qlml, klmh, klml);
  k_s2       <<<dim3(16,48),  256, 0, stream>>>(qlmh, qlml, kh, kl, s2f, stats);
  k_t1       <<<dim3(8,48),   256, 0, stream>>>(s2f, stats, vTh, vTl, t1p);
  k_mid      <<<48,           256, 0, stream>>>(qlmf, klmf, t1p, w2th, w2tl);
  k_final    <<<dim3(16,48),  256, 0, stream>>>(qh, ql, klmh, klml, w2th, w2tl, Hh, Hl);
  k_proj     <<<768,          256, 0, stream>>>(Hh, Hl, wph, wpl, bproj, out);
}

// Round 13
// 486.737 us; speedup vs baseline: 1.2040x; 1.0168x over previous
//
#include <hip/hip_runtime.h>

typedef unsigned short u16;
typedef __attribute__((ext_vector_type(8))) short bf16x8;
typedef __attribute__((ext_vector_type(8))) unsigned short u16x8;
typedef __attribute__((ext_vector_type(4))) unsigned short u16x4;
typedef __attribute__((ext_vector_type(4))) float f32x4;

#define NB 4
#define NH 12
#define NSEQ 4096
#define NC 768
#define ND 64
#define NM 64
#define NBH 48

__device__ __forceinline__ float b2f(u16 u){ unsigned v = ((unsigned)u)<<16; return __builtin_bit_cast(float, v); }
__device__ __forceinline__ u16 f2b(float f){ unsigned u = __builtin_bit_cast(unsigned, f); u = u + 0x7FFFu + ((u>>16)&1u); return (u16)(u>>16); }
__device__ __forceinline__ void split2(float f, u16& h, u16& l){
  h = f2b(f);
  l = f2b(f - b2f(h));
}

typedef const __attribute__((address_space(1))) unsigned int guint;
typedef __attribute__((address_space(3))) unsigned int luint;
__device__ __forceinline__ void gload16(const void* g, void* l){
  __builtin_amdgcn_global_load_lds((guint*)g, (luint*)l, 16, 0, 0);
}

__device__ __forceinline__ f32x4 mfma16x16(bf16x8 a, bf16x8 b, f32x4 c){
  return __builtin_amdgcn_mfma_f32_16x16x32_bf16(a, b, c, 0, 0, 0);
}

// ---------------- merged split: f32 -> (hi,lo) bf16 pairs for x, wqkv, wproj ----------------
#define NX4 3145728
#define NWQ4 442368
#define NWP4 147456
__global__ __launch_bounds__(256) void k_split3(const float* __restrict__ x, const float* __restrict__ wq,
                                                const float* __restrict__ wp,
                                                u16* __restrict__ xh, u16* __restrict__ xl,
                                                u16* __restrict__ wqh, u16* __restrict__ wql,
                                                u16* __restrict__ wph, u16* __restrict__ wpl){
  int i = blockIdx.x*256 + threadIdx.x;
  const float* src; u16 *dh, *dl; int j;
  if (i < NX4){ src = x; dh = xh; dl = xl; j = i; }
  else if (i < NX4+NWQ4){ src = wq; dh = wqh; dl = wql; j = i - NX4; }
  else if (i < NX4+NWQ4+NWP4){ src = wp; dh = wph; dl = wpl; j = i - NX4 - NWQ4; }
  else return;
  f32x4 v = ((const f32x4*)src)[j];
  u16x4 hh, ll;
  #pragma unroll
  for (int e=0;e<4;++e){ u16 hb, lb; split2(v[e], hb, lb); hh[e]=hb; ll[e]=lb; }
  ((u16x4*)dh)[j] = hh; ((u16x4*)dl)[j] = ll;
}

// ============ 128x128 BK=64 split-bf16 GEMM, T2-swizzled LDS (0-conflict), XCD-swizzled grid ====

// ---------------- big GEMM 1: qkv = X @ Wqkv^T; q/k row-major + fused pooling; v transposed ----------------
__global__ __launch_bounds__(256) void k_qkv(const u16* __restrict__ xh, const u16* __restrict__ xl,
                                             const u16* __restrict__ wh, const u16* __restrict__ wl,
                                             u16* __restrict__ qh, u16* __restrict__ ql,
                                             u16* __restrict__ kh, u16* __restrict__ kl,
                                             u16* __restrict__ vTh, u16* __restrict__ vTl,
                                             float* __restrict__ qlmf, float* __restrict__ klmf,
                                             u16* __restrict__ qlmh, u16* __restrict__ qlml,
                                             u16* __restrict__ klmh, u16* __restrict__ klml){
  __shared__ u16 lds[32768];   // 64 KB: Ah | Al | Bh | Bl (8192 u16 each)
  const int K = NC;
  int tid = threadIdx.x, wave = tid>>6, lane = tid&63;
  int wm = wave>>1, wn = wave&1;
  int bid = blockIdx.x;                    // 2304 blocks, %8==0
  int swz = (bid&7)*288 + (bid>>3);        // bijective XCD swizzle
  int bx = swz % 18, by = swz / 18;        // n-fastest within XCD chunk -> A-panel locality
  int m0 = by*128, n0 = bx*128;
  int srow = lane>>3;
  int scol = ((lane&7) ^ srow)*8;          // pre-swizzled global column
  const u16* src0; u16* dst0;
  if (wave==0){ src0 = xh + (size_t)m0*K; dst0 = lds; }
  else if (wave==1){ src0 = xl + (size_t)m0*K; dst0 = lds+8192; }
  else if (wave==2){ src0 = wh + (size_t)n0*K; dst0 = lds+16384; }
  else            { src0 = wl + (size_t)n0*K; dst0 = lds+24576; }
  f32x4 acc[4][4] = {};
  for (int k0=0; k0<K; k0+=64){
    #pragma unroll
    for (int it=0; it<16; ++it){
      int r = it*8;
      gload16(&src0[(size_t)(r+srow)*K + k0 + scol], &dst0[r*64]);
    }
    __syncthreads();
    #pragma unroll
    for (int kk=0; kk<2; ++kk){
      int sl = ((kk*4 + (lane>>4)) ^ (lane&7))*8;   // swizzled read slot
      bf16x8 a_h[4], a_l[4], b_h[4], b_l[4];
      #pragma unroll
      for (int i=0;i<4;++i){
        int ro = (wm*64+i*16+(lane&15))*64 + sl;
        a_h[i] = *(const bf16x8*)&lds[ro]; a_l[i] = *(const bf16x8*)&lds[8192+ro];
      }
      #pragma unroll
      for (int j=0;j<4;++j){
        int ro = (wn*64+j*16+(lane&15))*64 + sl;
        b_h[j] = *(const bf16x8*)&lds[16384+ro]; b_l[j] = *(const bf16x8*)&lds[24576+ro];
      }
      #pragma unroll
      for (int i=0;i<4;++i)
        #pragma unroll
        for (int j=0;j<4;++j){
          acc[i][j] = mfma16x16(a_h[i], b_h[j], acc[i][j]);
          acc[i][j] = mfma16x16(a_h[i], b_l[j], acc[i][j]);
          acc[i][j] = mfma16x16(a_l[i], b_h[j], acc[i][j]);
        }
    }
    __syncthreads();
  }
  int rb = (lane>>4)*4, cb = lane&15;
  int b_ = m0>>12, nlo = m0&4095;
  if (n0 < 1536){
    // ---- q or k block: row-major stores + fused segment pooling ----
    int s = n0/768;
    u16* dh = s ? kh : qh;
    u16* dl = s ? kl : ql;
    float* lmf = s ? klmf : qlmf;
    u16* lmh = s ? klmh : qlmh;
    u16* lml = s ? klml : qlml;
    #pragma unroll
    for (int j=0;j<4;++j){
      int gn = n0 + wn*64 + j*16 + cb;
      int rem = gn - s*768; int hd = rem>>6, d = rem&63;
      #pragma unroll
      for (int i=0;i<4;++i)
        #pragma unroll
        for (int r=0;r<4;++r){
          int n = nlo + wm*64 + i*16 + rb + r;
          size_t idx = (((size_t)(b_*NH + hd))*NSEQ + n)*ND + d;
          u16 hb, lb; split2(acc[i][j][r], hb, lb);
          dh[idx] = hb; dl[idx] = lb;
        }
      float tot = 0.f;
      #pragma unroll
      for (int i=0;i<4;++i)
        #pragma unroll
        for (int r=0;r<4;++r) tot += acc[i][j][r];
      tot += __shfl_xor(tot, 16);
      tot += __shfl_xor(tot, 32);
      if (lane < 16){
        int lseg = (nlo>>6) + wm;
        float mean = tot * (1.f/64.f);
        size_t o = (((size_t)(b_*NH + hd))*NM + lseg)*ND + d;
        lmf[o] = mean;
        u16 hb, lb; split2(mean, hb, lb);
        lmh[o] = hb; lml[o] = lb;
      }
    }
  } else {
    // ---- v block: transpose 128x128 tile via LDS, coalesced vT writes ----
    const int TS = 136;
    #pragma unroll
    for (int part=0; part<2; ++part){
      __syncthreads();
      #pragma unroll
      for (int j=0;j<4;++j){
        int dcol = wn*64 + j*16 + cb;
        #pragma unroll
        for (int i=0;i<4;++i)
          #pragma unroll
          for (int r=0;r<4;++r){
            int nrow = wm*64 + i*16 + rb + r;
            u16 hb, lb; split2(acc[i][j][r], hb, lb);
            lds[dcol*TS + nrow] = part ? lb : hb;
          }
      }
      __syncthreads();
      int drow = tid>>1, half = (tid&1)*64;
      int remd = (n0 - 1536) + drow;
      int hd = remd>>6, dd = remd&63;
      u16* dst = (part ? vTl : vTh) + (((size_t)(b_*NH + hd))*ND + dd)*NSEQ + nlo + half;
      const u16* srcl = &lds[drow*TS + half];
      #pragma unroll
      for (int e=0;e<8;++e)
        *(u16x8*)(dst + e*8) = *(const u16x8*)(srcl + e*8);
    }
  }
}

// ---------------- big GEMM 2: out = H @ Wproj^T + bias (f32 out) ----------------
__global__ __launch_bounds__(256) void k_proj(const u16* __restrict__ Hh, const u16* __restrict__ Hl,
                                              const u16* __restrict__ wh, const u16* __restrict__ wl,
                                              const float* __restrict__ bias, float* __restrict__ out){
  __shared__ u16 lds[32768];
  const int K = NC;
  int tid = threadIdx.x, wave = tid>>6, lane = tid&63;
  int wm = wave>>1, wn = wave&1;
  int bid = blockIdx.x;                    // 768 blocks, %8==0
  int swz = (bid&7)*96 + (bid>>3);
  int bx = swz % 6, by = swz / 6;
  int m0 = by*128, n0 = bx*128;
  int srow = lane>>3;
  int scol = ((lane&7) ^ srow)*8;
  const u16* src0; u16* dst0;
  if (wave==0){ src0 = Hh + (size_t)m0*K; dst0 = lds; }
  else if (wave==1){ src0 = Hl + (size_t)m0*K; dst0 = lds+8192; }
  else if (wave==2){ src0 = wh + (size_t)n0*K; dst0 = lds+16384; }
  else            { src0 = wl + (size_t)n0*K; dst0 = lds+24576; }
  f32x4 acc[4][4] = {};
  for (int k0=0; k0<K; k0+=64){
    #pragma unroll
    for (int it=0; it<16; ++it){
      int r = it*8;
      gload16(&src0[(size_t)(r+srow)*K + k0 + scol], &dst0[r*64]);
    }
    __syncthreads();
    #pragma unroll
    for (int kk=0; kk<2; ++kk){
      int sl = ((kk*4 + (lane>>4)) ^ (lane&7))*8;
      bf16x8 a_h[4], a_l[4], b_h[4], b_l[4];
      #pragma unroll
      for (int i=0;i<4;++i){
        int ro = (wm*64+i*16+(lane&15))*64 + sl;
        a_h[i] = *(const bf16x8*)&lds[ro]; a_l[i] = *(const bf16x8*)&lds[8192+ro];
      }
      #pragma unroll
      for (int j=0;j<4;++j){
        int ro = (wn*64+j*16+(lane&15))*64 + sl;
        b_h[j] = *(const bf16x8*)&lds[16384+ro]; b_l[j] = *(const bf16x8*)&lds[24576+ro];
      }
      #pragma unroll
      for (int i=0;i<4;++i)
        #pragma unroll
        for (int j=0;j<4;++j){
          acc[i][j] = mfma16x16(a_h[i], b_h[j], acc[i][j]);
          acc[i][j] = mfma16x16(a_h[i], b_l[j], acc[i][j]);
          acc[i][j] = mfma16x16(a_l[i], b_h[j], acc[i][j]);
        }
    }
    __syncthreads();
  }
  int rb = (lane>>4)*4, cb = lane&15;
  #pragma unroll
  for (int j=0;j<4;++j){
    int gn = n0 + wn*64 + j*16 + cb;
    float bb = bias[gn];
    #pragma unroll
    for (int i=0;i<4;++i){
      #pragma unroll
      for (int r=0;r<4;++r){
        int gm = m0 + wm*64 + i*16 + rb + r;
        out[(size_t)gm*NC + gn] = acc[i][j][r] + bb;
      }
    }
  }
}

// ---------------- fused attention middle: t1p[kb][bh] = softmax-online(q_lm @ k^T / 8) @ v ----------------
// grid (8,48), 256 thr. Per wave: 16 q_lm rows; 8 chunks of 64 cols with online softmax.
// Outputs UNNORMALIZED pv + per-row (m,l) stats; k_mid combines exactly.
__global__ __launch_bounds__(256) void k_fat1(const u16* __restrict__ qlmh, const u16* __restrict__ qlml,
                                              const u16* __restrict__ kh, const u16* __restrict__ kl,
                                              const u16* __restrict__ vTh, const u16* __restrict__ vTl,
                                              float* __restrict__ t1p, float* __restrict__ st2){
  __shared__ u16 Ph[4096], Pl[4096];   // 4 waves x [16][64] bf16 pair
  int kb = blockIdx.x, bh = blockIdx.y;
  int tid = threadIdx.x, wave = tid>>6, lane = tid&63;
  int la = lane&15, hi = lane>>4;
  u16* Pwh = Ph + wave*1024;
  u16* Pwl = Pl + wave*1024;
  // q_lm A-frags: rows wave*16+la, K=64
  bf16x8 qa_h[2], qa_l[2];
  #pragma unroll
  for (int kk=0;kk<2;++kk){
    size_t ro = ((size_t)bh*NM + wave*16 + la)*ND + kk*32 + hi*8;
    qa_h[kk] = *(const bf16x8*)&qlmh[ro];
    qa_l[kk] = *(const bf16x8*)&qlml[ro];
  }
  float m_[4] = {-1e30f,-1e30f,-1e30f,-1e30f};
  float l_[4] = {0.f,0.f,0.f,0.f};
  f32x4 pv[4] = {};
  for (int ch=0; ch<8; ++ch){
    int nbase = kb*512 + ch*64;
    // ---- QK chunk: S[16 rows][64 cols] ----
    f32x4 s_[4] = {};
    #pragma unroll
    for (int kk=0;kk<2;++kk){
      int koff = kk*32 + hi*8;
      #pragma unroll
      for (int j=0;j<4;++j){
        size_t ro = ((size_t)bh*NSEQ + nbase + j*16 + la)*ND + koff;
        bf16x8 b_h = *(const bf16x8*)&kh[ro];
        bf16x8 b_l = *(const bf16x8*)&kl[ro];
        s_[j] = mfma16x16(qa_h[kk], b_h, s_[j]);
        s_[j] = mfma16x16(qa_h[kk], b_l, s_[j]);
        s_[j] = mfma16x16(qa_l[kk], b_h, s_[j]);
      }
    }
    // ---- online softmax per row (row = hi*4+r); write P pair to LDS (k_final's swizzle) ----
    #pragma unroll
    for (int r=0;r<4;++r){
      float v0=s_[0][r]*0.125f, v1=s_[1][r]*0.125f, v2=s_[2][r]*0.125f, v3=s_[3][r]*0.125f;
      float mx = fmaxf(fmaxf(v0,v1), fmaxf(v2,v3));
      #pragma unroll
      for (int off=1; off<16; off<<=1) mx = fmaxf(mx, __shfl_xor(mx, off));
      float mn = fmaxf(m_[r], mx);
      float fr = __expf(m_[r] - mn);
      float p0=__expf(v0-mn), p1=__expf(v1-mn), p2=__expf(v2-mn), p3=__expf(v3-mn);
      float se = p0+p1+p2+p3;
      #pragma unroll
      for (int off=1; off<16; off<<=1) se += __shfl_xor(se, off);
      l_[r] = l_[r]*fr + se;
      m_[r] = mn;
      pv[0][r]*=fr; pv[1][r]*=fr; pv[2][r]*=fr; pv[3][r]*=fr;
      int row = hi*4 + r;
      float pj0=p0, pj1=p1, pj2=p2, pj3=p3;
      #pragma unroll
      for (int j=0;j<4;++j){
        float pval = (j==0)?pj0:(j==1)?pj1:(j==2)?pj2:pj3;
        u16 hb, lb; split2(pval, hb, lb);
        int col = j*16 + la;
        int scol = (((col>>3) ^ (row&7))<<3) | (col&7);
        Pwh[row*64 + scol] = hb;
        Pwl[row*64 + scol] = lb;
      }
    }
    // ---- PV: A = P rows (from LDS, swizzled read), B = vT rows d ----
    #pragma unroll
    for (int kk=0;kk<2;++kk){
      int sl2 = ((kk*4 + hi) ^ (la&7))*8;
      bf16x8 pa_h = *(const bf16x8*)&Pwh[la*64 + sl2];
      bf16x8 pa_l = *(const bf16x8*)&Pwl[la*64 + sl2];
      int koff = nbase + kk*32 + hi*8;
      #pragma unroll
      for (int j=0;j<4;++j){
        size_t ro = ((size_t)bh*ND + j*16 + la)*NSEQ + koff;
        bf16x8 b_h = *(const bf16x8*)&vTh[ro];
        bf16x8 b_l = *(const bf16x8*)&vTl[ro];
        pv[j] = mfma16x16(pa_h, b_h, pv[j]);
        pv[j] = mfma16x16(pa_h, b_l, pv[j]);
        pv[j] = mfma16x16(pa_l, b_h, pv[j]);
      }
    }
  }
  // ---- store pv (unnormalized) + stats ----
  #pragma unroll
  for (int j=0;j<4;++j)
    #pragma unroll
    for (int r=0;r<4;++r){
      int row = wave*16 + hi*4 + r;
      int d = j*16 + la;
      t1p[(((size_t)(kb*NBH + bh))*NM + row)*ND + d] = pv[j][r];
    }
  if (la == 0){
    #pragma unroll
    for (int r=0;r<4;++r){
      int row = wave*16 + hi*4 + r;
      size_t o = (((size_t)(kb*NBH + bh))*NM + row)*2;
      st2[o] = m_[r]; st2[o+1] = l_[r];
    }
  }
}

// ---------------- mid (4-wave): Gram+softmax -> M; T = exact-combine(t1p,st2); GJ solve [M|T] -> X
__global__ __launch_bounds__(256) void k_mid(const float* __restrict__ qlmf, const float* __restrict__ klmf,
                                            const float* __restrict__ t1p, const float* __restrict__ st2,
                                            u16* __restrict__ w2th, u16* __restrict__ w2tl){
  __shared__ float M[64*68];
  __shared__ float T[64*68];
  __shared__ int piv_s;
  int bh = blockIdx.x, tid = threadIdx.x;
  int r = tid>>2, qd = tid&3;           // row, 16-col quad
  const float* qrow  = qlmf + (size_t)bh*NM*ND + r*64;
  const float* kbase = klmf + (size_t)bh*NM*ND;
  float qv[64];
  #pragma unroll
  for (int e=0;e<16;++e){
    f32x4 t4 = ((const f32x4*)qrow)[e];
    qv[e*4]=t4[0]; qv[e*4+1]=t4[1]; qv[e*4+2]=t4[2]; qv[e*4+3]=t4[3];
  }
  float sv[16];
  #pragma unroll
  for (int mi=0;mi<16;++mi){
    const float* krow = kbase + (size_t)(qd*16+mi)*64;
    float a = 0.f;
    #pragma unroll
    for (int e=0;e<16;++e){
      f32x4 k4 = ((const f32x4*)krow)[e];
      a += qv[e*4]*k4[0] + qv[e*4+1]*k4[1] + qv[e*4+2]*k4[2] + qv[e*4+3]*k4[3];
    }
    sv[mi] = a*0.125f;
  }
  float mx = sv[0];
  #pragma unroll
  for (int mi=1;mi<16;++mi) mx = fmaxf(mx, sv[mi]);
  mx = fmaxf(mx, __shfl_xor(mx,1)); mx = fmaxf(mx, __shfl_xor(mx,2));
  float sum = 0.f;
  #pragma unroll
  for (int mi=0;mi<16;++mi){ sv[mi] = __expf(sv[mi]-mx); sum += sv[mi]; }
  sum += __shfl_xor(sum,1); sum += __shfl_xor(sum,2);
  float sinv = 1.f/sum;
  #pragma unroll
  for (int mi=0;mi<16;++mi){
    int m = qd*16+mi;
    float p = sv[mi]*sinv;
    if (m == r) p += 1e-4f;
    M[r*68+m] = p;
  }
  // ---- T: exact two-level softmax combine of 8 split partials ----
  float Mx = -1e30f;
  #pragma unroll
  for (int kb2=0;kb2<8;++kb2)
    Mx = fmaxf(Mx, st2[(((size_t)(kb2*NBH + bh))*NM + r)*2]);
  float L = 0.f; float wsc[8];
  #pragma unroll
  for (int kb2=0;kb2<8;++kb2){
    size_t o = (((size_t)(kb2*NBH + bh))*NM + r)*2;
    float w = __expf(st2[o] - Mx);
    wsc[kb2] = w;
    L += w * st2[o+1];
  }
  float Linv = 1.f / L;
  #pragma unroll
  for (int q=0;q<4;++q){
    int c = qd*16 + q*4;
    f32x4 a = {};
    #pragma unroll
    for (int kb2=0;kb2<8;++kb2)
      a += wsc[kb2] * *(const f32x4*)&t1p[((size_t)(kb2*NBH + bh)*NM + r)*ND + c];
    *(f32x4*)&T[r*68+c] = a * Linv;
  }
  __syncthreads();
  for (int kp=0; kp<64; ++kp){
    if (tid < 64){
      float val = (tid >= kp) ? fabsf(M[tid*68+kp]) : -1.f;
      int idx = tid;
      #pragma unroll
      for (int off=32; off; off>>=1){
        float ov = __shfl_xor(val, off); int oi = __shfl_xor(idx, off);
        if (ov > val || (ov == val && oi < idx)){ val = ov; idx = oi; }
      }
      if (tid == 0) piv_s = idx;
    }
    __syncthreads();
    int p = piv_s;
    if (r == kp){
      float pinv = 1.f / M[p*68+kp];
      f32x4 mk[4], mp[4], tk[4], tp_[4];
      #pragma unroll
      for (int q=0;q<4;++q){
        int c = qd*16 + q*4;
        mk[q] = *(const f32x4*)&M[kp*68+c]; mp[q] = *(const f32x4*)&M[p*68+c];
        tk[q] = *(const f32x4*)&T[kp*68+c]; tp_[q] = *(const f32x4*)&T[p*68+c];
      }
      #pragma unroll
      for (int q=0;q<4;++q){
        int c = qd*16 + q*4;
        *(f32x4*)&M[p*68+c] = mk[q];       *(f32x4*)&T[p*68+c] = tk[q];
        *(f32x4*)&M[kp*68+c] = mp[q]*pinv; *(f32x4*)&T[kp*68+c] = tp_[q]*pinv;
      }
    }
    __syncthreads();
    if (r != kp){
      float f = M[r*68+kp];
      #pragma unroll
      for (int q=0;q<4;++q){
        int c = qd*16 + q*4;
        f32x4 pm = *(const f32x4*)&M[kp*68+c];
        f32x4 om = *(const f32x4*)&M[r*68+c];
        *(f32x4*)&M[r*68+c] = om - f*pm;
        f32x4 pt = *(const f32x4*)&T[kp*68+c];
        f32x4 ot = *(const f32x4*)&T[r*68+c];
        *(f32x4*)&T[r*68+c] = ot - f*pt;
      }
    }
    __syncthreads();
  }
  int d = tid>>2, qs = tid&3;
  #pragma unroll
  for (int li=0; li<16; ++li){
    int l = qs*16 + li;
    float xv = T[l*68 + d];
    u16 hb, lb; split2(xv, hb, lb);
    size_t o = ((size_t)bh*ND + d)*NM + l;
    w2th[o] = hb; w2tl[o] = lb;
  }
}

// ---------------- final: P1 = softmax(q@k_lm^T*scale); h = P1 @ w2 -> pair ----------------
__global__ __launch_bounds__(256) void k_final(const u16* __restrict__ qh, const u16* __restrict__ ql,
                                               const u16* __restrict__ klmh, const u16* __restrict__ klml,
                                               const u16* __restrict__ w2th, const u16* __restrict__ w2tl,
                                               u16* __restrict__ Hh, u16* __restrict__ Hl){
  __shared__ u16 Ph[4*4096], Pl[4*4096];
  int chunk = blockIdx.x, bh = blockIdx.y;
  int b_ = bh/NH, hd = bh - b_*NH;
  int tid = threadIdx.x, wave = tid>>6, lane = tid&63;
  int n0 = chunk*256 + wave*64;
  const u16* qhp = qh + ((size_t)bh*NSEQ + n0)*ND;
  const u16* qlp = ql + ((size_t)bh*NSEQ + n0)*ND;
  const u16* Kh = klmh + (size_t)bh*NM*ND;
  const u16* Kl = klml + (size_t)bh*NM*ND;
  const u16* Wh = w2th + (size_t)bh*ND*NM;
  const u16* Wl = w2tl + (size_t)bh*ND*NM;
  u16* Phw = Ph + wave*4096;
  u16* Plw = Pl + wave*4096;
  f32x4 accs[4][4] = {};
  #pragma unroll
  for (int kk=0; kk<2; ++kk){
    int koff = kk*32 + (lane>>4)*8;
    bf16x8 a_h[4], a_l[4], b_h[4], b_l[4];
    #pragma unroll
    for (int i=0;i<4;++i){
      size_t ro = (size_t)(i*16+(lane&15))*ND + koff;
      a_h[i] = *(const bf16x8*)&qhp[ro]; a_l[i] = *(const bf16x8*)&qlp[ro];
    }
    #pragma unroll
    for (int j=0;j<4;++j){
      size_t ro = (size_t)(j*16+(lane&15))*ND + koff;
      b_h[j] = *(const bf16x8*)&Kh[ro]; b_l[j] = *(const bf16x8*)&Kl[ro];
    }
    #pragma unroll
    for (int i=0;i<4;++i)
      #pragma unroll
      for (int j=0;j<4;++j){
        accs[i][j] = mfma16x16(a_h[i], b_h[j], accs[i][j]);
        accs[i][j] = mfma16x16(a_h[i], b_l[j], accs[i][j]);
        accs[i][j] = mfma16x16(a_l[i], b_h[j], accs[i][j]);
      }
  }
  #pragma unroll
  for (int i=0;i<4;++i)
    #pragma unroll
    for (int j=0;j<4;++j) accs[i][j] *= 0.125f;
  int rb = (lane>>4)*4, cb = lane&15;
  #pragma unroll
  for (int i=0;i<4;++i){
    #pragma unroll
    for (int r=0;r<4;++r){
      float mx = -1e30f;
      #pragma unroll
      for (int j=0;j<4;++j) mx = fmaxf(mx, accs[i][j][r]);
      #pragma unroll
      for (int off=1; off<16; off<<=1) mx = fmaxf(mx, __shfl_xor(mx, off));
      float e[4]; float sum = 0.f;
      #pragma unroll
      for (int j=0;j<4;++j){ e[j] = __expf(accs[i][j][r]-mx); sum += e[j]; }
      #pragma unroll
      for (int off=1; off<16; off<<=1) sum += __shfl_xor(sum, off);
      float inv = 1.f/sum;
      int row = i*16 + rb + r;
      #pragma unroll
      for (int j=0;j<4;++j){
        u16 hb, lb; split2(e[j]*inv, hb, lb);
        int col = j*16 + cb;
        int scol = (((col>>3) ^ (row&7))<<3) | (col&7);   // swizzled P store
        Phw[row*64 + scol] = hb;
        Plw[row*64 + scol] = lb;
      }
    }
  }
  __syncthreads();
  f32x4 acco[4][4] = {};
  #pragma unroll
  for (int kk=0; kk<2; ++kk){
    int koff = kk*32 + (lane>>4)*8;
    int sl = ((kk*4 + (lane>>4)) ^ (lane&7))*8;           // swizzled P read
    bf16x8 a_h[4], a_l[4], b_h[4], b_l[4];
    #pragma unroll
    for (int i=0;i<4;++i){
      int ro = (i*16+(lane&15))*64 + sl;
      a_h[i] = *(const bf16x8*)&Phw[ro]; a_l[i] = *(const bf16x8*)&Plw[ro];
    }
    #pragma unroll
    for (int j=0;j<4;++j){
      size_t ro = (size_t)(j*16+(lane&15))*64 + koff;
      b_h[j] = *(const bf16x8*)&Wh[ro]; b_l[j] = *(const bf16x8*)&Wl[ro];
    }
    #pragma unroll
    for (int i=0;i<4;++i)
      #pragma unroll
      for (int j=0;j<4;++j){
        acco[i][j] = mfma16x16(a_h[i], b_h[j], acco[i][j]);
        acco[i][j] = mfma16x16(a_h[i], b_l[j], acco[i][j]);
        acco[i][j] = mfma16x16(a_l[i], b_h[j], acco[i][j]);
      }
  }
  #pragma unroll
  for (int i=0;i<4;++i)
    #pragma unroll
    for (int j=0;j<4;++j)
      #pragma unroll
      for (int r=0;r<4;++r){
        int n = n0 + i*16 + rb + r;
        int d = j*16 + cb;
        size_t o = ((size_t)(b_*NSEQ + n))*NC + hd*64 + d;
        u16 hb, lb; split2(acco[i][j][r], hb, lb);
        Hh[o] = hb; Hl[o] = lb;
      }
}

__global__ void k_sent(float* out){ out[0] = 1.0e9f; }

// ---------------- workspace layout (bytes) ----------------
#define OFF_QH     0ull
#define OFF_QL     25165824ull
#define OFF_KH     50331648ull
#define OFF_KL     75497472ull
#define OFF_VTH    100663296ull   /* v written directly transposed by k_qkv */
#define OFF_VTL    125829120ull
#define OFF_S2     150994944ull   /* xh/xl during split+qkv; Hh/Hl after k_fat1 */
#define OFF_QLMF   201326592ull
#define OFF_KLMF   202113024ull
#define OFF_QLMH   202899456ull
#define OFF_QLML   203292672ull
#define OFF_KLMH   203685888ull
#define OFF_KLML   204079104ull
#define OFF_W2TH   204472320ull
#define OFF_W2TL   204865536ull
#define OFF_T1P    205258752ull
#define OFF_WQH    211550208ull   /* wqkv-hi during split+qkv; (m,l) stats after (192 KB) */
#define OFF_WQL    215089152ull
#define OFF_WPH    218628096ull
#define OFF_WPL    219807744ull
#define WS_NEEDED  220987392ull

extern "C" void kernel_launch(void* const* d_in, const int* in_sizes, int n_in,
                              void* d_out, int out_size, void* d_ws, size_t ws_size,
                              hipStream_t stream){
  const float* x     = (const float*)d_in[0];
  const float* wqkv  = (const float*)d_in[1];
  const float* wproj = (const float*)d_in[2];
  const float* bproj = (const float*)d_in[3];
  float* out = (float*)d_out;
  char* ws = (char*)d_ws;
  if (ws_size < WS_NEEDED){ k_sent<<<1,1,0,stream>>>(out); return; }
  u16* qh = (u16*)(ws + OFF_QH);  u16* ql = (u16*)(ws + OFF_QL);
  u16* kh = (u16*)(ws + OFF_KH);  u16* kl = (u16*)(ws + OFF_KL);
  u16* vTh = (u16*)(ws + OFF_VTH); u16* vTl = (u16*)(ws + OFF_VTL);
  u16* xh = (u16*)(ws + OFF_S2);                // alias: region reused during split+qkv
  u16* xl = (u16*)(ws + OFF_S2 + 25165824ull);
  u16* Hh = (u16*)(ws + OFF_S2);                // alias: h pair after xh/xl dead
  u16* Hl = (u16*)(ws + OFF_S2 + 25165824ull);
  float* qlmf = (float*)(ws + OFF_QLMF);
  float* klmf = (float*)(ws + OFF_KLMF);
  u16* qlmh = (u16*)(ws + OFF_QLMH); u16* qlml = (u16*)(ws + OFF_QLML);
  u16* klmh = (u16*)(ws + OFF_KLMH); u16* klml = (u16*)(ws + OFF_KLML);
  u16* w2th = (u16*)(ws + OFF_W2TH); u16* w2tl = (u16*)(ws + OFF_W2TL);
  float* t1p = (float*)(ws + OFF_T1P);
  u16* wqh = (u16*)(ws + OFF_WQH); u16* wql = (u16*)(ws + OFF_WQL);
  u16* wph = (u16*)(ws + OFF_WPH); u16* wpl = (u16*)(ws + OFF_WPL);
  float* st2 = (float*)(ws + OFF_WQH);          // alias: wqh dead after k_qkv (192 KB used)

  k_split3   <<<14592, 256, 0, stream>>>(x, wqkv, wproj, xh, xl, wqh, wql, wph, wpl);
  k_qkv      <<<2304, 256, 0, stream>>>(xh, xl, wqh, wql, qh, ql, kh, kl, vTh, vTl,
                                        qlmf, klmf, qlmh, qlml, klmh, klml);
  k_fat1     <<<dim3(8,48),   256, 0, stream>>>(qlmh, qlml, kh, kl, vTh, vTl, t1p, st2);
  k_mid      <<<48,           256, 0, stream>>>(qlmf, klmf, t1p, st2, w2th, w2tl);
  k_final    <<<dim3(16,48),  256, 0, stream>>>(qh, ql, klmh, klml, w2th, w2tl, Hh, Hl);
  k_proj     <<<768,          256, 0, stream>>>(Hh, Hl, wph, wpl, bproj, out);
}